// Round 1
// baseline (7695.178 us; speedup 1.0000x reference)
//
#include <hip/hip_runtime.h>
#include <stdint.h>
#include <stddef.h>

#define CDIV(a,b) (((a)+(b)-1)/(b))

#define N_CFG  50000
#define N_AST  200000
#define N_TEST 1000
#define NNODE  (N_CFG + N_AST + N_TEST)

// ---------------------------------------------------------------- CSR build
__global__ void zero_int_kernel(int* __restrict__ p, int n) {
  int i = blockIdx.x * 256 + threadIdx.x;
  if (i < n) p[i] = 0;
}

__global__ void hist_kernel(const int* __restrict__ dst, int E, int* __restrict__ cnt) {
  int i = blockIdx.x * 256 + threadIdx.x;
  if (i < E) atomicAdd(&cnt[dst[i]], 1);
}

__global__ void copy_int_kernel(int* __restrict__ d, const int* __restrict__ s, int n) {
  int i = blockIdx.x * 256 + threadIdx.x;
  if (i < n) d[i] = s[i];
}

__global__ __launch_bounds__(1024) void scan_kernel(const int* __restrict__ cnt,
                                                    int* __restrict__ rp, int n) {
  __shared__ int wsum[16];
  __shared__ int carry;
  int tid = threadIdx.x;
  int lane = tid & 63, wid = tid >> 6;
  if (tid == 0) { carry = 0; rp[0] = 0; }
  __syncthreads();
  for (int base = 0; base < n; base += 1024) {
    int i = base + tid;
    int v = (i < n) ? cnt[i] : 0;
    int s = v;
    #pragma unroll
    for (int o = 1; o < 64; o <<= 1) {
      int t = __shfl_up(s, o, 64);
      if (lane >= o) s += t;
    }
    if (lane == 63) wsum[wid] = s;
    __syncthreads();
    if (wid == 0) {
      int x = (lane < 16) ? wsum[lane] : 0;
      #pragma unroll
      for (int o = 1; o < 16; o <<= 1) {
        int t = __shfl_up(x, o, 64);
        if (lane >= o) x += t;
      }
      if (lane < 16) wsum[lane] = x;
    }
    __syncthreads();
    int off = carry + (wid > 0 ? wsum[wid - 1] : 0);
    if (i < n) rp[i + 1] = off + s;
    __syncthreads();
    if (tid == 0) carry += wsum[15];
    __syncthreads();
  }
}

__global__ void scatter_kernel(const int* __restrict__ src, const int* __restrict__ dst, int E,
                               int* __restrict__ cursor, int* __restrict__ outidx) {
  int i = blockIdx.x * 256 + threadIdx.x;
  if (i < E) {
    int p = atomicAdd(&cursor[dst[i]], 1);
    outidx[p] = src[i];
  }
}

// ---------------------------------------------------------------- encoders
__global__ void gather_lbl_kernel(const int* __restrict__ labels, const float* __restrict__ emb,
                                  float* __restrict__ h, int n) {
  int i = blockIdx.x * 256 + threadIdx.x;   // n*32 work items (128 floats per node)
  int node = i >> 5, l = i & 31;
  if (node < n) {
    float4 v = ((const float4*)(emb + (size_t)labels[node] * 128))[l];
    ((float4*)(h + (size_t)node * 256))[l] = v;
  }
}

__global__ void bcast_temb_kernel(const float* __restrict__ t, float* __restrict__ h) {
  int i = blockIdx.x * 256 + threadIdx.x;   // N_TEST*64
  int node = i >> 6, l = i & 63;
  if (node < N_TEST) ((float4*)(h + (size_t)node * 256))[l] = ((const float4*)t)[l];
}

// c_content[M,300] @ W[300,128] + b -> h[row*256 + 128 + col]
__global__ __launch_bounds__(256) void gemm_enc_kernel(
    const float* __restrict__ A, int M,
    const float* __restrict__ B, const float* __restrict__ bias,
    float* __restrict__ h) {
  __shared__ float As[16][132];
  __shared__ float Bs[16][132];
  int tid = threadIdx.x;
  int bm0 = blockIdx.x * 128;
  int ar = tid >> 2, ac4 = tid & 3;
  int bk = tid >> 5, bn4 = tid & 31;
  int tx = tid & 15, ty = tid >> 4;
  float acc[2][2][4][4];
  #pragma unroll
  for (int a = 0; a < 2; ++a)
    #pragma unroll
    for (int bq = 0; bq < 2; ++bq)
      #pragma unroll
      for (int j = 0; j < 4; ++j)
        #pragma unroll
        for (int i = 0; i < 4; ++i) acc[a][bq][j][i] = 0.f;

  const int KT = 19;  // ceil(300/16)
  for (int kt = 0; kt < KT; ++kt) {
    __syncthreads();
    int k0 = kt * 16;
    #pragma unroll
    for (int hh = 0; hh < 2; ++hh) {
      int row = bm0 + ar + hh * 64;
      int c = k0 + ac4 * 4;
      float4 av = make_float4(0.f, 0.f, 0.f, 0.f);
      if (row < M) {
        if (c + 3 < 300) {
          av = *(const float4*)(A + (size_t)row * 300 + c);
        } else {
          float* avp = &av.x;
          for (int j = 0; j < 4; ++j)
            if (c + j < 300) avp[j] = A[(size_t)row * 300 + c + j];
        }
      }
      As[ac4 * 4 + 0][ar + hh * 64] = av.x;
      As[ac4 * 4 + 1][ar + hh * 64] = av.y;
      As[ac4 * 4 + 2][ar + hh * 64] = av.z;
      As[ac4 * 4 + 3][ar + hh * 64] = av.w;
    }
    #pragma unroll
    for (int hh = 0; hh < 2; ++hh) {
      int kk = bk + hh * 8;
      int kg = k0 + kk;
      float4 bv = make_float4(0.f, 0.f, 0.f, 0.f);
      if (kg < 300) bv = *(const float4*)(B + (size_t)kg * 128 + bn4 * 4);
      *(float4*)&Bs[kk][bn4 * 4] = bv;
    }
    __syncthreads();
    #pragma unroll
    for (int kk = 0; kk < 16; ++kk) {
      float4 a0 = *(const float4*)&As[kk][ty * 4];
      float4 a1 = *(const float4*)&As[kk][64 + ty * 4];
      float4 b0 = *(const float4*)&Bs[kk][tx * 4];
      float4 b1 = *(const float4*)&Bs[kk][64 + tx * 4];
      const float av[2][4] = {{a0.x, a0.y, a0.z, a0.w}, {a1.x, a1.y, a1.z, a1.w}};
      const float bv[2][4] = {{b0.x, b0.y, b0.z, b0.w}, {b1.x, b1.y, b1.z, b1.w}};
      #pragma unroll
      for (int qm = 0; qm < 2; ++qm)
        #pragma unroll
        for (int j = 0; j < 4; ++j) {
          float a = av[qm][j];
          #pragma unroll
          for (int qn = 0; qn < 2; ++qn)
            #pragma unroll
            for (int i = 0; i < 4; ++i)
              acc[qm][qn][j][i] = fmaf(a, bv[qn][i], acc[qm][qn][j][i]);
        }
    }
  }
  #pragma unroll
  for (int qm = 0; qm < 2; ++qm)
    #pragma unroll
    for (int j = 0; j < 4; ++j) {
      int row = bm0 + qm * 64 + ty * 4 + j;
      if (row >= M) continue;
      #pragma unroll
      for (int qn = 0; qn < 2; ++qn) {
        int lc = qn * 64 + tx * 4;
        float4 v;
        v.x = acc[qm][qn][j][0] + bias[lc + 0];
        v.y = acc[qm][qn][j][1] + bias[lc + 1];
        v.z = acc[qm][qn][j][2] + bias[lc + 2];
        v.w = acc[qm][qn][j][3] + bias[lc + 3];
        *(float4*)(h + (size_t)row * 256 + 128 + lc) = v;
      }
    }
}

// ---------------------------------------------------------------- aggregation
// A[w, colOff:colOff+256] = sum over CSR edges of h_src[src][0:256]
__global__ void agg_kernel(const float* __restrict__ hsrc, const int* __restrict__ rp,
                           const int* __restrict__ si, float* __restrict__ A,
                           int strideF, int colOff, int n) {
  int w = (blockIdx.x * blockDim.x + threadIdx.x) >> 6;
  int lane = threadIdx.x & 63;
  if (w >= n) return;
  int b = rp[w], e = rp[w + 1];
  float4 acc = make_float4(0.f, 0.f, 0.f, 0.f);
  for (int i = b; i < e; ++i) {
    float4 v = ((const float4*)(hsrc + (size_t)si[i] * 256))[lane];
    acc.x += v.x; acc.y += v.y; acc.z += v.z; acc.w += v.w;
  }
  ((float4*)(A + (size_t)w * strideF + colOff))[lane] = acc;
}

// ---------------------------------------------------------------- layer GEMM
// out[row,0:256] = relu(A[row,0:K] @ stacked W_rel + sum(b_rel)) (+ residual)
__global__ __launch_bounds__(256) void gemm_layer_kernel(
    const float* __restrict__ A, int M, int K,
    const float* __restrict__ Wrel, const float* __restrict__ brel, int layer,
    int r0, int r1, int r2,
    const float* __restrict__ residual, float* __restrict__ out) {
  __shared__ float As[16][132];
  __shared__ float Bs[16][132];
  __shared__ float biasS[128];
  int tid = threadIdx.x;
  int bm0 = blockIdx.x * 128;
  int n0  = blockIdx.y * 128;
  int rels[3] = {r0, r1, r2};

  if (tid < 128) {
    int col = n0 + tid;
    float s = brel[((size_t)layer * 6 + r0) * 256 + col];
    if (r1 >= 0) s += brel[((size_t)layer * 6 + r1) * 256 + col];
    if (r2 >= 0) s += brel[((size_t)layer * 6 + r2) * 256 + col];
    biasS[tid] = s;
  }

  int ar = tid >> 2, ac4 = tid & 3;
  int bk = tid >> 5, bn4 = tid & 31;
  int tx = tid & 15, ty = tid >> 4;
  float acc[2][2][4][4];
  #pragma unroll
  for (int a = 0; a < 2; ++a)
    #pragma unroll
    for (int bq = 0; bq < 2; ++bq)
      #pragma unroll
      for (int j = 0; j < 4; ++j)
        #pragma unroll
        for (int i = 0; i < 4; ++i) acc[a][bq][j][i] = 0.f;

  int KT = K >> 4;
  for (int kt = 0; kt < KT; ++kt) {
    __syncthreads();
    #pragma unroll
    for (int hh = 0; hh < 2; ++hh) {
      int row = bm0 + ar + hh * 64;
      float4 av = make_float4(0.f, 0.f, 0.f, 0.f);
      if (row < M) av = *(const float4*)(A + (size_t)row * K + kt * 16 + ac4 * 4);
      As[ac4 * 4 + 0][ar + hh * 64] = av.x;
      As[ac4 * 4 + 1][ar + hh * 64] = av.y;
      As[ac4 * 4 + 2][ar + hh * 64] = av.z;
      As[ac4 * 4 + 3][ar + hh * 64] = av.w;
    }
    #pragma unroll
    for (int hh = 0; hh < 2; ++hh) {
      int kk = bk + hh * 8;
      int kg = kt * 16 + kk;
      int rel = rels[kg >> 8];
      const float* bp = Wrel + ((((size_t)layer * 6 + rel) * 256 + (kg & 255)) * 256) + n0 + bn4 * 4;
      *(float4*)&Bs[kk][bn4 * 4] = *(const float4*)bp;
    }
    __syncthreads();
    #pragma unroll
    for (int kk = 0; kk < 16; ++kk) {
      float4 a0 = *(const float4*)&As[kk][ty * 4];
      float4 a1 = *(const float4*)&As[kk][64 + ty * 4];
      float4 b0 = *(const float4*)&Bs[kk][tx * 4];
      float4 b1 = *(const float4*)&Bs[kk][64 + tx * 4];
      const float av[2][4] = {{a0.x, a0.y, a0.z, a0.w}, {a1.x, a1.y, a1.z, a1.w}};
      const float bv[2][4] = {{b0.x, b0.y, b0.z, b0.w}, {b1.x, b1.y, b1.z, b1.w}};
      #pragma unroll
      for (int qm = 0; qm < 2; ++qm)
        #pragma unroll
        for (int j = 0; j < 4; ++j) {
          float a = av[qm][j];
          #pragma unroll
          for (int qn = 0; qn < 2; ++qn)
            #pragma unroll
            for (int i = 0; i < 4; ++i)
              acc[qm][qn][j][i] = fmaf(a, bv[qn][i], acc[qm][qn][j][i]);
        }
    }
  }
  #pragma unroll
  for (int qm = 0; qm < 2; ++qm)
    #pragma unroll
    for (int j = 0; j < 4; ++j) {
      int row = bm0 + qm * 64 + ty * 4 + j;
      if (row >= M) continue;
      #pragma unroll
      for (int qn = 0; qn < 2; ++qn) {
        int lc = qn * 64 + tx * 4;
        int col = n0 + lc;
        float4 v;
        v.x = fmaxf(acc[qm][qn][j][0] + biasS[lc + 0], 0.f);
        v.y = fmaxf(acc[qm][qn][j][1] + biasS[lc + 1], 0.f);
        v.z = fmaxf(acc[qm][qn][j][2] + biasS[lc + 2], 0.f);
        v.w = fmaxf(acc[qm][qn][j][3] + biasS[lc + 3], 0.f);
        if (residual) {
          float4 r = *(const float4*)(residual + (size_t)row * 256 + col);
          v.x += r.x; v.y += r.y; v.z += r.z; v.w += r.w;
        }
        *(float4*)(out + (size_t)row * 256 + col) = v;
      }
    }
}

// ---------------------------------------------------------------- decoders
__global__ void decode2_kernel(const float* __restrict__ h, const float* __restrict__ W,
                               const float* __restrict__ b, float* __restrict__ logits,
                               float* __restrict__ soft, int n) {
  int w = (blockIdx.x * blockDim.x + threadIdx.x) >> 6;
  int lane = threadIdx.x & 63;
  if (w >= n) return;
  float4 v = ((const float4*)(h + (size_t)w * 256))[lane];
  int k = lane * 4;
  float l0 = v.x * W[(k + 0) * 2 + 0] + v.y * W[(k + 1) * 2 + 0] +
             v.z * W[(k + 2) * 2 + 0] + v.w * W[(k + 3) * 2 + 0];
  float l1 = v.x * W[(k + 0) * 2 + 1] + v.y * W[(k + 1) * 2 + 1] +
             v.z * W[(k + 2) * 2 + 1] + v.w * W[(k + 3) * 2 + 1];
  #pragma unroll
  for (int m = 1; m < 64; m <<= 1) {
    l0 += __shfl_xor(l0, m, 64);
    l1 += __shfl_xor(l1, m, 64);
  }
  if (lane == 0) {
    l0 += b[0]; l1 += b[1];
    float mx = fmaxf(l0, l1);
    float e0 = expf(l0 - mx), e1 = expf(l1 - mx);
    float s = e0 + e1;
    logits[(size_t)w * 2 + 0] = l0;
    logits[(size_t)w * 2 + 1] = l1;
    soft[(size_t)w * 2 + 0] = e0 / s;
    soft[(size_t)w * 2 + 1] = e1 / s;
  }
}

__global__ void decode3_kernel(const float* __restrict__ h, const float* __restrict__ W,
                               const float* __restrict__ b, float* __restrict__ logits,
                               float* __restrict__ soft, int n) {
  int w = (blockIdx.x * blockDim.x + threadIdx.x) >> 6;
  int lane = threadIdx.x & 63;
  if (w >= n) return;
  float4 v = ((const float4*)(h + (size_t)w * 256))[lane];
  int k = lane * 4;
  float l0 = v.x * W[(k + 0) * 3 + 0] + v.y * W[(k + 1) * 3 + 0] +
             v.z * W[(k + 2) * 3 + 0] + v.w * W[(k + 3) * 3 + 0];
  float l1 = v.x * W[(k + 0) * 3 + 1] + v.y * W[(k + 1) * 3 + 1] +
             v.z * W[(k + 2) * 3 + 1] + v.w * W[(k + 3) * 3 + 1];
  float l2 = v.x * W[(k + 0) * 3 + 2] + v.y * W[(k + 1) * 3 + 2] +
             v.z * W[(k + 2) * 3 + 2] + v.w * W[(k + 3) * 3 + 2];
  #pragma unroll
  for (int m = 1; m < 64; m <<= 1) {
    l0 += __shfl_xor(l0, m, 64);
    l1 += __shfl_xor(l1, m, 64);
    l2 += __shfl_xor(l2, m, 64);
  }
  if (lane == 0) {
    l0 += b[0]; l1 += b[1]; l2 += b[2];
    float mx = fmaxf(fmaxf(l0, l1), l2);
    float e0 = expf(l0 - mx), e1 = expf(l1 - mx), e2 = expf(l2 - mx);
    float s = e0 + e1 + e2;
    logits[(size_t)w * 3 + 0] = l0;
    logits[(size_t)w * 3 + 1] = l1;
    logits[(size_t)w * 3 + 2] = l2;
    soft[(size_t)w * 3 + 0] = e0 / s;
    soft[(size_t)w * 3 + 1] = e1 / s;
    soft[(size_t)w * 3 + 2] = e2 / s;
  }
}

// ---------------------------------------------------------------- host
extern "C" void kernel_launch(void* const* d_in, const int* in_sizes, int n_in,
                              void* d_out, int out_size, void* d_ws, size_t ws_size,
                              hipStream_t stream) {
  (void)in_sizes; (void)n_in; (void)out_size; (void)ws_size;
  const int*   c_labels  = (const int*)  d_in[0];
  const float* c_content = (const float*)d_in[1];
  const int*   a_labels  = (const int*)  d_in[2];
  const float* a_content = (const float*)d_in[3];
  const int*   edges[6];
  for (int r = 0; r < 6; ++r) edges[r] = (const int*)d_in[4 + r];
  const float* c_lbl_emb = (const float*)d_in[10];
  const float* c_enc_W   = (const float*)d_in[11];
  const float* c_enc_b   = (const float*)d_in[12];
  const float* a_lbl_emb = (const float*)d_in[13];
  const float* a_enc_W   = (const float*)d_in[14];
  const float* a_enc_b   = (const float*)d_in[15];
  const float* t_emb     = (const float*)d_in[16];
  const float* W_rel     = (const float*)d_in[17];
  const float* b_rel     = (const float*)d_in[18];
  const float* dec_W     = (const float*)d_in[19];
  const float* dec_b     = (const float*)d_in[20];
  const float* adec_W    = (const float*)d_in[21];
  const float* adec_b    = (const float*)d_in[22];
  float* out = (float*)d_out;

  static const int E_CNT[6]   = {200000, 400000, 200000, 200000, 50000, 50000};
  static const int REL_DSTN[6] = {N_CFG, N_AST, N_CFG, N_AST, N_TEST, N_CFG};

  char* ws = (char*)d_ws;
  size_t off = 0;
  auto alloc = [&](size_t bytes) -> void* {
    void* p = ws + off;
    off += (bytes + 255) & ~(size_t)255;
    return p;
  };
  float* buf0 = (float*)alloc((size_t)NNODE * 256 * 4);
  float* buf1 = (float*)alloc((size_t)NNODE * 256 * 4);
  float* Abuf = (float*)alloc((size_t)N_AST * 512 * 4);   // shared A scratch (max: ast 200k x 512)
  int* rowptr[6];
  int* srcidx[6];
  for (int r = 0; r < 6; ++r) rowptr[r] = (int*)alloc((size_t)(REL_DSTN[r] + 1) * 4);
  for (int r = 0; r < 6; ++r) srcidx[r] = (int*)alloc((size_t)E_CNT[r] * 4);
  int* cursor = (int*)alloc((size_t)(N_AST + 1) * 4);

  // CSR (dst-sorted) per relation
  for (int r = 0; r < 6; ++r) {
    int nd = REL_DSTN[r], E = E_CNT[r];
    const int* esrc = edges[r];
    const int* edst = edges[r] + E;
    zero_int_kernel<<<CDIV(nd, 256), 256, 0, stream>>>(cursor, nd);
    hist_kernel<<<CDIV(E, 256), 256, 0, stream>>>(edst, E, cursor);
    scan_kernel<<<1, 1024, 0, stream>>>(cursor, rowptr[r], nd);
    copy_int_kernel<<<CDIV(nd, 256), 256, 0, stream>>>(cursor, rowptr[r], nd);
    scatter_kernel<<<CDIV(E, 256), 256, 0, stream>>>(esrc, edst, E, cursor, srcidx[r]);
  }

  const size_t OFF_CFG = 0;
  const size_t OFF_AST = (size_t)N_CFG * 256;
  const size_t OFF_TST = (size_t)(N_CFG + N_AST) * 256;

  // encoders -> buf0
  gather_lbl_kernel<<<CDIV(N_CFG * 32, 256), 256, 0, stream>>>(c_labels, c_lbl_emb, buf0 + OFF_CFG, N_CFG);
  gather_lbl_kernel<<<CDIV(N_AST * 32, 256), 256, 0, stream>>>(a_labels, a_lbl_emb, buf0 + OFF_AST, N_AST);
  gemm_enc_kernel<<<dim3(CDIV(N_CFG, 128), 1), 256, 0, stream>>>(c_content, N_CFG, c_enc_W, c_enc_b, buf0 + OFF_CFG);
  gemm_enc_kernel<<<dim3(CDIV(N_AST, 128), 1), 256, 0, stream>>>(a_content, N_AST, a_enc_W, a_enc_b, buf0 + OFF_AST);
  bcast_temb_kernel<<<CDIV(N_TEST * 64, 256), 256, 0, stream>>>(t_emb, buf0 + OFF_TST);

  float* h_in = buf0;
  float* h_out = buf1;
  for (int l = 0; l < 5; ++l) {
    bool use_res = (l == 1 || l == 3);
    // dst cfg: rels 0(cc: src cfg), 2(ac: src ast), 5(tc: src test); K = 768
    agg_kernel<<<CDIV(N_CFG, 4), 256, 0, stream>>>(h_in + OFF_CFG, rowptr[0], srcidx[0], Abuf, 768, 0,   N_CFG);
    agg_kernel<<<CDIV(N_CFG, 4), 256, 0, stream>>>(h_in + OFF_AST, rowptr[2], srcidx[2], Abuf, 768, 256, N_CFG);
    agg_kernel<<<CDIV(N_CFG, 4), 256, 0, stream>>>(h_in + OFF_TST, rowptr[5], srcidx[5], Abuf, 768, 512, N_CFG);
    gemm_layer_kernel<<<dim3(CDIV(N_CFG, 128), 2), 256, 0, stream>>>(
        Abuf, N_CFG, 768, W_rel, b_rel, l, 0, 2, 5,
        use_res ? h_in + OFF_CFG : nullptr, h_out + OFF_CFG);
    // dst ast: rels 1(aa: src ast), 3(ca: src cfg); K = 512
    agg_kernel<<<CDIV(N_AST, 4), 256, 0, stream>>>(h_in + OFF_AST, rowptr[1], srcidx[1], Abuf, 512, 0,   N_AST);
    agg_kernel<<<CDIV(N_AST, 4), 256, 0, stream>>>(h_in + OFF_CFG, rowptr[3], srcidx[3], Abuf, 512, 256, N_AST);
    gemm_layer_kernel<<<dim3(CDIV(N_AST, 128), 2), 256, 0, stream>>>(
        Abuf, N_AST, 512, W_rel, b_rel, l, 1, 3, -1,
        use_res ? h_in + OFF_AST : nullptr, h_out + OFF_AST);
    // dst test: rel 4(ct: src cfg); K = 256
    agg_kernel<<<CDIV(N_TEST, 4), 256, 0, stream>>>(h_in + OFF_CFG, rowptr[4], srcidx[4], Abuf, 256, 0, N_TEST);
    gemm_layer_kernel<<<dim3(CDIV(N_TEST, 128), 2), 256, 0, stream>>>(
        Abuf, N_TEST, 256, W_rel, b_rel, l, 4, -1, -1,
        use_res ? h_in + OFF_TST : nullptr, h_out + OFF_TST);
    float* t = h_in; h_in = h_out; h_out = t;
  }

  decode2_kernel<<<CDIV(N_CFG, 4), 256, 0, stream>>>(h_in + OFF_CFG, dec_W, dec_b,
                                                     out, out + 100000, N_CFG);
  decode3_kernel<<<CDIV(N_AST, 4), 256, 0, stream>>>(h_in + OFF_AST, adec_W, adec_b,
                                                     out + 200000, out + 800000, N_AST);
}

// Round 2
// 4199.677 us; speedup vs baseline: 1.8323x; 1.8323x over previous
//
#include <hip/hip_runtime.h>
#include <stdint.h>
#include <stddef.h>

#define CDIV(a,b) (((a)+(b)-1)/(b))

#define N_CFG  50000
#define N_AST  200000
#define N_TEST 1000
#define NNODE  (N_CFG + N_AST + N_TEST)

typedef __attribute__((ext_vector_type(8))) short bf16x8;
typedef __attribute__((ext_vector_type(4))) short s16x4;
typedef __attribute__((ext_vector_type(4))) float f32x4;

__device__ __forceinline__ unsigned short f2bf(float f) {
  union { float f; unsigned int u; } x; x.f = f;
  unsigned int r = x.u + 0x7fffu + ((x.u >> 16) & 1u);   // RNE
  return (unsigned short)(r >> 16);
}

__device__ __forceinline__ void gload_lds16(const void* g, void* l) {
  __builtin_amdgcn_global_load_lds((const __attribute__((address_space(1))) unsigned int*)g,
                                   (__attribute__((address_space(3))) unsigned int*)l,
                                   16, 0, 0);
}

// ---------------------------------------------------------------- CSR build
__global__ void zero_int_kernel(int* __restrict__ p, int n) {
  int i = blockIdx.x * 256 + threadIdx.x;
  if (i < n) p[i] = 0;
}

__global__ void hist_kernel(const int* __restrict__ dst, int E, int* __restrict__ cnt) {
  int i = blockIdx.x * 256 + threadIdx.x;
  if (i < E) atomicAdd(&cnt[dst[i]], 1);
}

__global__ void copy_int_kernel(int* __restrict__ d, const int* __restrict__ s, int n) {
  int i = blockIdx.x * 256 + threadIdx.x;
  if (i < n) d[i] = s[i];
}

__global__ __launch_bounds__(1024) void scan_kernel(const int* __restrict__ cnt,
                                                    int* __restrict__ rp, int n) {
  __shared__ int wsum[16];
  __shared__ int carry;
  int tid = threadIdx.x;
  int lane = tid & 63, wid = tid >> 6;
  if (tid == 0) { carry = 0; rp[0] = 0; }
  __syncthreads();
  for (int base = 0; base < n; base += 1024) {
    int i = base + tid;
    int v = (i < n) ? cnt[i] : 0;
    int s = v;
    #pragma unroll
    for (int o = 1; o < 64; o <<= 1) {
      int t = __shfl_up(s, o, 64);
      if (lane >= o) s += t;
    }
    if (lane == 63) wsum[wid] = s;
    __syncthreads();
    if (wid == 0) {
      int x = (lane < 16) ? wsum[lane] : 0;
      #pragma unroll
      for (int o = 1; o < 16; o <<= 1) {
        int t = __shfl_up(x, o, 64);
        if (lane >= o) x += t;
      }
      if (lane < 16) wsum[lane] = x;
    }
    __syncthreads();
    int off = carry + (wid > 0 ? wsum[wid - 1] : 0);
    if (i < n) rp[i + 1] = off + s;
    __syncthreads();
    if (tid == 0) carry += wsum[15];
    __syncthreads();
  }
}

__global__ void scatter_kernel(const int* __restrict__ src, const int* __restrict__ dst, int E,
                               int* __restrict__ cursor, int* __restrict__ outidx) {
  int i = blockIdx.x * 256 + threadIdx.x;
  if (i < E) {
    int p = atomicAdd(&cursor[dst[i]], 1);
    outidx[p] = src[i];
  }
}

// ---------------------------------------------------------------- encoders
__global__ void gather_lbl_kernel(const int* __restrict__ labels, const float* __restrict__ emb,
                                  float* __restrict__ h, int n) {
  int i = blockIdx.x * 256 + threadIdx.x;
  int node = i >> 5, l = i & 31;
  if (node < n) {
    float4 v = ((const float4*)(emb + (size_t)labels[node] * 128))[l];
    ((float4*)(h + (size_t)node * 256))[l] = v;
  }
}

__global__ void bcast_temb_kernel(const float* __restrict__ t, float* __restrict__ h) {
  int i = blockIdx.x * 256 + threadIdx.x;
  int node = i >> 6, l = i & 63;
  if (node < N_TEST) ((float4*)(h + (size_t)node * 256))[l] = ((const float4*)t)[l];
}

// c_content[M,300] @ W[300,128] + b -> h[row*256 + 128 + col]  (fp32)
__global__ __launch_bounds__(256) void gemm_enc_kernel(
    const float* __restrict__ A, int M,
    const float* __restrict__ B, const float* __restrict__ bias,
    float* __restrict__ h) {
  __shared__ float As[16][132];
  __shared__ float Bs[16][132];
  int tid = threadIdx.x;
  int bm0 = blockIdx.x * 128;
  int ar = tid >> 2, ac4 = tid & 3;
  int bk = tid >> 5, bn4 = tid & 31;
  int tx = tid & 15, ty = tid >> 4;
  float acc[2][2][4][4];
  #pragma unroll
  for (int a = 0; a < 2; ++a)
    #pragma unroll
    for (int bq = 0; bq < 2; ++bq)
      #pragma unroll
      for (int j = 0; j < 4; ++j)
        #pragma unroll
        for (int i = 0; i < 4; ++i) acc[a][bq][j][i] = 0.f;

  const int KT = 19;
  for (int kt = 0; kt < KT; ++kt) {
    __syncthreads();
    int k0 = kt * 16;
    #pragma unroll
    for (int hh = 0; hh < 2; ++hh) {
      int row = bm0 + ar + hh * 64;
      int c = k0 + ac4 * 4;
      float4 av = make_float4(0.f, 0.f, 0.f, 0.f);
      if (row < M) {
        if (c + 3 < 300) {
          av = *(const float4*)(A + (size_t)row * 300 + c);
        } else {
          float* avp = &av.x;
          for (int j = 0; j < 4; ++j)
            if (c + j < 300) avp[j] = A[(size_t)row * 300 + c + j];
        }
      }
      As[ac4 * 4 + 0][ar + hh * 64] = av.x;
      As[ac4 * 4 + 1][ar + hh * 64] = av.y;
      As[ac4 * 4 + 2][ar + hh * 64] = av.z;
      As[ac4 * 4 + 3][ar + hh * 64] = av.w;
    }
    #pragma unroll
    for (int hh = 0; hh < 2; ++hh) {
      int kk = bk + hh * 8;
      int kg = k0 + kk;
      float4 bv = make_float4(0.f, 0.f, 0.f, 0.f);
      if (kg < 300) bv = *(const float4*)(B + (size_t)kg * 128 + bn4 * 4);
      *(float4*)&Bs[kk][bn4 * 4] = bv;
    }
    __syncthreads();
    #pragma unroll
    for (int kk = 0; kk < 16; ++kk) {
      float4 a0 = *(const float4*)&As[kk][ty * 4];
      float4 a1 = *(const float4*)&As[kk][64 + ty * 4];
      float4 b0 = *(const float4*)&Bs[kk][tx * 4];
      float4 b1 = *(const float4*)&Bs[kk][64 + tx * 4];
      const float av[2][4] = {{a0.x, a0.y, a0.z, a0.w}, {a1.x, a1.y, a1.z, a1.w}};
      const float bv[2][4] = {{b0.x, b0.y, b0.z, b0.w}, {b1.x, b1.y, b1.z, b1.w}};
      #pragma unroll
      for (int qm = 0; qm < 2; ++qm)
        #pragma unroll
        for (int j = 0; j < 4; ++j) {
          float a = av[qm][j];
          #pragma unroll
          for (int qn = 0; qn < 2; ++qn)
            #pragma unroll
            for (int i = 0; i < 4; ++i)
              acc[qm][qn][j][i] = fmaf(a, bv[qn][i], acc[qm][qn][j][i]);
        }
    }
  }
  #pragma unroll
  for (int qm = 0; qm < 2; ++qm)
    #pragma unroll
    for (int j = 0; j < 4; ++j) {
      int row = bm0 + qm * 64 + ty * 4 + j;
      if (row >= M) continue;
      #pragma unroll
      for (int qn = 0; qn < 2; ++qn) {
        int lc = qn * 64 + tx * 4;
        float4 v;
        v.x = acc[qm][qn][j][0] + bias[lc + 0];
        v.y = acc[qm][qn][j][1] + bias[lc + 1];
        v.z = acc[qm][qn][j][2] + bias[lc + 2];
        v.w = acc[qm][qn][j][3] + bias[lc + 3];
        *(float4*)(h + (size_t)row * 256 + 128 + lc) = v;
      }
    }
}

// ---------------------------------------------------------------- W -> bf16 transpose
// W_rel fp32 [5][6][K=256][N=256]  ->  Wt bf16 [5][6][N=256][K=256]
__global__ void wt_kernel(const float* __restrict__ W, unsigned short* __restrict__ Wt) {
  int i = blockIdx.x * 256 + threadIdx.x;       // out-index (write-coalesced)
  int k = i & 255, n = (i >> 8) & 255, lr = i >> 16;
  Wt[i] = f2bf(W[((size_t)lr * 256 + k) * 256 + n]);
}

// ---------------------------------------------------------------- aggregation (fp32 acc -> bf16 out)
__global__ void agg_bf16_kernel(const float* __restrict__ hsrc, const int* __restrict__ rp,
                                const int* __restrict__ si, unsigned short* __restrict__ A,
                                int strideK, int colOff, int n) {
  int w = (blockIdx.x * blockDim.x + threadIdx.x) >> 6;
  int lane = threadIdx.x & 63;
  if (w >= n) return;
  int b = rp[w], e = rp[w + 1];
  float4 acc = make_float4(0.f, 0.f, 0.f, 0.f);
  for (int i = b; i < e; ++i) {
    float4 v = ((const float4*)(hsrc + (size_t)si[i] * 256))[lane];
    acc.x += v.x; acc.y += v.y; acc.z += v.z; acc.w += v.w;
  }
  s16x4 o;
  o.x = (short)f2bf(acc.x); o.y = (short)f2bf(acc.y);
  o.z = (short)f2bf(acc.z); o.w = (short)f2bf(acc.w);
  *(s16x4*)(A + (size_t)w * strideK + colOff + lane * 4) = o;
}

// ---------------------------------------------------------------- MFMA layer GEMM
// out[row,0:256] = relu(A[row,0:K]@[W_r0;W_r1;W_r2] + sum b) (+residual)
// A: bf16 [M rnd up to 128][K]; Wt_layer: bf16 [6][256 n][256 k]
__global__ __launch_bounds__(256) void gemm_mfma_kernel(
    const unsigned short* __restrict__ A, int M, int K,
    const unsigned short* __restrict__ Wt,
    const float* __restrict__ brel, int layer, int r0, int r1, int r2,
    const float* __restrict__ residual, float* __restrict__ out) {
  __shared__ __align__(16) unsigned short As[2][8192];   // [128 m][64 k] swizzled
  __shared__ __align__(16) unsigned short Bs[2][8192];   // [128 n][64 k] swizzled
  __shared__ float biasS[128];
  int tid = threadIdx.x, lane = tid & 63, wid = tid >> 6;
  int gm0 = blockIdx.x * 128;
  int n0  = blockIdx.y * 128;
  int rels[3] = {r0, r1, r2};

  if (tid < 128) {
    int col = n0 + tid;
    float s = brel[((size_t)layer * 6 + r0) * 256 + col];
    if (r1 >= 0) s += brel[((size_t)layer * 6 + r1) * 256 + col];
    if (r2 >= 0) s += brel[((size_t)layer * 6 + r2) * 256 + col];
    biasS[tid] = s;
  }

  int wr = wid >> 1, wc = wid & 1;
  f32x4 acc[4][4];
  #pragma unroll
  for (int mi = 0; mi < 4; ++mi)
    #pragma unroll
    for (int ni = 0; ni < 4; ++ni) acc[mi][ni] = (f32x4){0.f, 0.f, 0.f, 0.f};

  // stage one 128x64 bf16 tile pair (A,B) for K-step kt into buffer `buf`.
  // LDS dest is linear (wave-uniform base + lane*16); the XOR swizzle is applied
  // by permuting the per-lane GLOBAL source (rule: both-sides-or-neither).
  auto stage = [&](int buf, int kt) {
    int k0 = kt * 64;
    #pragma unroll
    for (int i = 0; i < 4; ++i) {                 // A: 16 instrs, this wave does wid*4+i
      int instr = wid * 4 + i;
      int P = instr * 64 + lane;                  // physical 16B slot
      int row = P >> 3, sp = P & 7;
      int s = sp ^ (row & 7);                     // logical k-slot living here
      const unsigned short* g = A + (size_t)(gm0 + row) * K + k0 + s * 8;
      gload_lds16(g, &As[buf][instr * 512]);
    }
    #pragma unroll
    for (int i = 0; i < 4; ++i) {                 // B: 16 instrs
      int instr = wid * 4 + i;
      int P = instr * 64 + lane;
      int row = P >> 3, sp = P & 7;
      int s = sp ^ (row & 7);
      const unsigned short* g = Wt + ((size_t)rels[k0 >> 8] * 256 + n0 + row) * 256
                                   + (k0 & 255) + s * 8;
      gload_lds16(g, &Bs[buf][instr * 512]);
    }
  };

  int nkt = K >> 6;
  stage(0, 0);
  __syncthreads();
  int cur = 0;
  for (int kt = 0; kt < nkt; ++kt) {
    if (kt + 1 < nkt) stage(cur ^ 1, kt + 1);
    #pragma unroll
    for (int kk = 0; kk < 2; ++kk) {
      bf16x8 af[4], bf[4];
      int slBase = kk * 4 + (lane >> 4);
      #pragma unroll
      for (int mi = 0; mi < 4; ++mi) {
        int row = wr * 64 + mi * 16 + (lane & 15);
        af[mi] = *(const bf16x8*)&As[cur][row * 64 + ((slBase ^ (row & 7)) * 8)];
      }
      #pragma unroll
      for (int ni = 0; ni < 4; ++ni) {
        int row = wc * 64 + ni * 16 + (lane & 15);
        bf[ni] = *(const bf16x8*)&Bs[cur][row * 64 + ((slBase ^ (row & 7)) * 8)];
      }
      #pragma unroll
      for (int mi = 0; mi < 4; ++mi)
        #pragma unroll
        for (int ni = 0; ni < 4; ++ni)
          acc[mi][ni] = __builtin_amdgcn_mfma_f32_16x16x32_bf16(af[mi], bf[ni], acc[mi][ni], 0, 0, 0);
    }
    __syncthreads();
    cur ^= 1;
  }

  #pragma unroll
  for (int mi = 0; mi < 4; ++mi)
    #pragma unroll
    for (int ni = 0; ni < 4; ++ni) {
      f32x4 v = acc[mi][ni];
      int coll = wc * 64 + ni * 16 + (lane & 15);
      int col = n0 + coll;
      #pragma unroll
      for (int j = 0; j < 4; ++j) {
        int row = gm0 + wr * 64 + mi * 16 + (lane >> 4) * 4 + j;
        if (row < M) {
          float x = fmaxf(v[j] + biasS[coll], 0.f);
          if (residual) x += residual[(size_t)row * 256 + col];
          out[(size_t)row * 256 + col] = x;
        }
      }
    }
}

// ---------------------------------------------------------------- decoders
__global__ void decode2_kernel(const float* __restrict__ h, const float* __restrict__ W,
                               const float* __restrict__ b, float* __restrict__ logits,
                               float* __restrict__ soft, int n) {
  int w = (blockIdx.x * blockDim.x + threadIdx.x) >> 6;
  int lane = threadIdx.x & 63;
  if (w >= n) return;
  float4 v = ((const float4*)(h + (size_t)w * 256))[lane];
  int k = lane * 4;
  float l0 = v.x * W[(k + 0) * 2 + 0] + v.y * W[(k + 1) * 2 + 0] +
             v.z * W[(k + 2) * 2 + 0] + v.w * W[(k + 3) * 2 + 0];
  float l1 = v.x * W[(k + 0) * 2 + 1] + v.y * W[(k + 1) * 2 + 1] +
             v.z * W[(k + 2) * 2 + 1] + v.w * W[(k + 3) * 2 + 1];
  #pragma unroll
  for (int m = 1; m < 64; m <<= 1) {
    l0 += __shfl_xor(l0, m, 64);
    l1 += __shfl_xor(l1, m, 64);
  }
  if (lane == 0) {
    l0 += b[0]; l1 += b[1];
    float mx = fmaxf(l0, l1);
    float e0 = expf(l0 - mx), e1 = expf(l1 - mx);
    float s = e0 + e1;
    logits[(size_t)w * 2 + 0] = l0;
    logits[(size_t)w * 2 + 1] = l1;
    soft[(size_t)w * 2 + 0] = e0 / s;
    soft[(size_t)w * 2 + 1] = e1 / s;
  }
}

__global__ void decode3_kernel(const float* __restrict__ h, const float* __restrict__ W,
                               const float* __restrict__ b, float* __restrict__ logits,
                               float* __restrict__ soft, int n) {
  int w = (blockIdx.x * blockDim.x + threadIdx.x) >> 6;
  int lane = threadIdx.x & 63;
  if (w >= n) return;
  float4 v = ((const float4*)(h + (size_t)w * 256))[lane];
  int k = lane * 4;
  float l0 = v.x * W[(k + 0) * 3 + 0] + v.y * W[(k + 1) * 3 + 0] +
             v.z * W[(k + 2) * 3 + 0] + v.w * W[(k + 3) * 3 + 0];
  float l1 = v.x * W[(k + 0) * 3 + 1] + v.y * W[(k + 1) * 3 + 1] +
             v.z * W[(k + 2) * 3 + 1] + v.w * W[(k + 3) * 3 + 1];
  float l2 = v.x * W[(k + 0) * 3 + 2] + v.y * W[(k + 1) * 3 + 2] +
             v.z * W[(k + 2) * 3 + 2] + v.w * W[(k + 3) * 3 + 2];
  #pragma unroll
  for (int m = 1; m < 64; m <<= 1) {
    l0 += __shfl_xor(l0, m, 64);
    l1 += __shfl_xor(l1, m, 64);
    l2 += __shfl_xor(l2, m, 64);
  }
  if (lane == 0) {
    l0 += b[0]; l1 += b[1]; l2 += b[2];
    float mx = fmaxf(fmaxf(l0, l1), l2);
    float e0 = expf(l0 - mx), e1 = expf(l1 - mx), e2 = expf(l2 - mx);
    float s = e0 + e1 + e2;
    logits[(size_t)w * 3 + 0] = l0;
    logits[(size_t)w * 3 + 1] = l1;
    logits[(size_t)w * 3 + 2] = l2;
    soft[(size_t)w * 3 + 0] = e0 / s;
    soft[(size_t)w * 3 + 1] = e1 / s;
    soft[(size_t)w * 3 + 2] = e2 / s;
  }
}

// ---------------------------------------------------------------- host
extern "C" void kernel_launch(void* const* d_in, const int* in_sizes, int n_in,
                              void* d_out, int out_size, void* d_ws, size_t ws_size,
                              hipStream_t stream) {
  (void)in_sizes; (void)n_in; (void)out_size; (void)ws_size;
  const int*   c_labels  = (const int*)  d_in[0];
  const float* c_content = (const float*)d_in[1];
  const int*   a_labels  = (const int*)  d_in[2];
  const float* a_content = (const float*)d_in[3];
  const int*   edges[6];
  for (int r = 0; r < 6; ++r) edges[r] = (const int*)d_in[4 + r];
  const float* c_lbl_emb = (const float*)d_in[10];
  const float* c_enc_W   = (const float*)d_in[11];
  const float* c_enc_b   = (const float*)d_in[12];
  const float* a_lbl_emb = (const float*)d_in[13];
  const float* a_enc_W   = (const float*)d_in[14];
  const float* a_enc_b   = (const float*)d_in[15];
  const float* t_emb     = (const float*)d_in[16];
  const float* W_rel     = (const float*)d_in[17];
  const float* b_rel     = (const float*)d_in[18];
  const float* dec_W     = (const float*)d_in[19];
  const float* dec_b     = (const float*)d_in[20];
  const float* adec_W    = (const float*)d_in[21];
  const float* adec_b    = (const float*)d_in[22];
  float* out = (float*)d_out;

  static const int E_CNT[6]    = {200000, 400000, 200000, 200000, 50000, 50000};
  static const int REL_DSTN[6] = {N_CFG, N_AST, N_CFG, N_AST, N_TEST, N_CFG};

  char* ws = (char*)d_ws;
  size_t off = 0;
  auto alloc = [&](size_t bytes) -> void* {
    void* p = ws + off;
    off += (bytes + 255) & ~(size_t)255;
    return p;
  };
  float* buf0 = (float*)alloc((size_t)NNODE * 256 * 4);
  float* buf1 = (float*)alloc((size_t)NNODE * 256 * 4);
  // bf16 A scratch; rows rounded up to 128 so MFMA tile tails read in-bounds
  unsigned short* Abuf = (unsigned short*)alloc((size_t)200064 * 512 * 2);
  unsigned short* Wt   = (unsigned short*)alloc((size_t)5 * 6 * 256 * 256 * 2);
  int* rowptr[6];
  int* srcidx[6];
  for (int r = 0; r < 6; ++r) rowptr[r] = (int*)alloc((size_t)(REL_DSTN[r] + 1) * 4);
  for (int r = 0; r < 6; ++r) srcidx[r] = (int*)alloc((size_t)E_CNT[r] * 4);
  int* cursor = (int*)alloc((size_t)(N_AST + 1) * 4);

  // weights -> bf16 transposed [l][r][n][k]
  wt_kernel<<<CDIV(5 * 6 * 256 * 256, 256), 256, 0, stream>>>(W_rel, Wt);

  // CSR (dst-sorted) per relation
  for (int r = 0; r < 6; ++r) {
    int nd = REL_DSTN[r], E = E_CNT[r];
    const int* esrc = edges[r];
    const int* edst = edges[r] + E;
    zero_int_kernel<<<CDIV(nd, 256), 256, 0, stream>>>(cursor, nd);
    hist_kernel<<<CDIV(E, 256), 256, 0, stream>>>(edst, E, cursor);
    scan_kernel<<<1, 1024, 0, stream>>>(cursor, rowptr[r], nd);
    copy_int_kernel<<<CDIV(nd, 256), 256, 0, stream>>>(cursor, rowptr[r], nd);
    scatter_kernel<<<CDIV(E, 256), 256, 0, stream>>>(esrc, edst, E, cursor, srcidx[r]);
  }

  const size_t OFF_CFG = 0;
  const size_t OFF_AST = (size_t)N_CFG * 256;
  const size_t OFF_TST = (size_t)(N_CFG + N_AST) * 256;

  // encoders -> buf0 (fp32)
  gather_lbl_kernel<<<CDIV(N_CFG * 32, 256), 256, 0, stream>>>(c_labels, c_lbl_emb, buf0 + OFF_CFG, N_CFG);
  gather_lbl_kernel<<<CDIV(N_AST * 32, 256), 256, 0, stream>>>(a_labels, a_lbl_emb, buf0 + OFF_AST, N_AST);
  gemm_enc_kernel<<<dim3(CDIV(N_CFG, 128), 1), 256, 0, stream>>>(c_content, N_CFG, c_enc_W, c_enc_b, buf0 + OFF_CFG);
  gemm_enc_kernel<<<dim3(CDIV(N_AST, 128), 1), 256, 0, stream>>>(a_content, N_AST, a_enc_W, a_enc_b, buf0 + OFF_AST);
  bcast_temb_kernel<<<CDIV(N_TEST * 64, 256), 256, 0, stream>>>(t_emb, buf0 + OFF_TST);

  float* h_in = buf0;
  float* h_out = buf1;
  for (int l = 0; l < 5; ++l) {
    bool use_res = (l == 1 || l == 3);
    const unsigned short* WtL = Wt + (size_t)l * 6 * 256 * 256;
    // dst cfg: rels 0(cc), 2(ac), 5(tc); K = 768
    agg_bf16_kernel<<<CDIV(N_CFG, 4), 256, 0, stream>>>(h_in + OFF_CFG, rowptr[0], srcidx[0], Abuf, 768, 0,   N_CFG);
    agg_bf16_kernel<<<CDIV(N_CFG, 4), 256, 0, stream>>>(h_in + OFF_AST, rowptr[2], srcidx[2], Abuf, 768, 256, N_CFG);
    agg_bf16_kernel<<<CDIV(N_CFG, 4), 256, 0, stream>>>(h_in + OFF_TST, rowptr[5], srcidx[5], Abuf, 768, 512, N_CFG);
    gemm_mfma_kernel<<<dim3(CDIV(N_CFG, 128), 2), 256, 0, stream>>>(
        Abuf, N_CFG, 768, WtL, b_rel, l, 0, 2, 5,
        use_res ? h_in + OFF_CFG : nullptr, h_out + OFF_CFG);
    // dst ast: rels 1(aa), 3(ca); K = 512
    agg_bf16_kernel<<<CDIV(N_AST, 4), 256, 0, stream>>>(h_in + OFF_AST, rowptr[1], srcidx[1], Abuf, 512, 0,   N_AST);
    agg_bf16_kernel<<<CDIV(N_AST, 4), 256, 0, stream>>>(h_in + OFF_CFG, rowptr[3], srcidx[3], Abuf, 512, 256, N_AST);
    gemm_mfma_kernel<<<dim3(CDIV(N_AST, 128), 2), 256, 0, stream>>>(
        Abuf, N_AST, 512, WtL, b_rel, l, 1, 3, -1,
        use_res ? h_in + OFF_AST : nullptr, h_out + OFF_AST);
    // dst test: rel 4(ct); K = 256
    agg_bf16_kernel<<<CDIV(N_TEST, 4), 256, 0, stream>>>(h_in + OFF_CFG, rowptr[4], srcidx[4], Abuf, 256, 0, N_TEST);
    gemm_mfma_kernel<<<dim3(CDIV(N_TEST, 128), 2), 256, 0, stream>>>(
        Abuf, N_TEST, 256, WtL, b_rel, l, 4, -1, -1,
        use_res ? h_in + OFF_TST : nullptr, h_out + OFF_TST);
    float* t = h_in; h_in = h_out; h_out = t;
  }

  decode2_kernel<<<CDIV(N_CFG, 4), 256, 0, stream>>>(h_in + OFF_CFG, dec_W, dec_b,
                                                     out, out + 100000, N_CFG);
  decode3_kernel<<<CDIV(N_AST, 4), 256, 0, stream>>>(h_in + OFF_AST, adec_W, adec_b,
                                                     out + 200000, out + 800000, N_AST);
}

// Round 3
// 3697.805 us; speedup vs baseline: 2.0810x; 1.1357x over previous
//
#include <hip/hip_runtime.h>
#include <stdint.h>
#include <stddef.h>

#define CDIV(a,b) (((a)+(b)-1)/(b))

#define N_CFG  50000
#define N_AST  200000
#define N_TEST 1000
#define NNODE  (N_CFG + N_AST + N_TEST)

typedef __attribute__((ext_vector_type(8))) short bf16x8;
typedef __attribute__((ext_vector_type(4))) short s16x4;
typedef __attribute__((ext_vector_type(4))) float f32x4;

__device__ __forceinline__ unsigned short f2bf(float f) {
  union { float f; unsigned int u; } x; x.f = f;
  unsigned int r = x.u + 0x7fffu + ((x.u >> 16) & 1u);   // RNE
  return (unsigned short)(r >> 16);
}
__device__ __forceinline__ float bf2f(unsigned short b) {
  union { unsigned int u; float f; } x; x.u = ((unsigned int)b) << 16;
  return x.f;
}

__device__ __forceinline__ void gload_lds16(const void* g, void* l) {
  __builtin_amdgcn_global_load_lds((const __attribute__((address_space(1))) unsigned int*)g,
                                   (__attribute__((address_space(3))) unsigned int*)l,
                                   16, 0, 0);
}

// ---------------------------------------------------------------- CSR build
__global__ void zero_int_kernel(int* __restrict__ p, int n) {
  int i = blockIdx.x * 256 + threadIdx.x;
  if (i < n) p[i] = 0;
}

__global__ void hist_kernel(const int* __restrict__ dst, int E, int* __restrict__ cnt) {
  int i = blockIdx.x * 256 + threadIdx.x;
  if (i < E) atomicAdd(&cnt[dst[i]], 1);
}

__global__ void copy_int_kernel(int* __restrict__ d, const int* __restrict__ s, int n) {
  int i = blockIdx.x * 256 + threadIdx.x;
  if (i < n) d[i] = s[i];
}

__global__ __launch_bounds__(1024) void scan_kernel(const int* __restrict__ cnt,
                                                    int* __restrict__ rp, int n) {
  __shared__ int wsum[16];
  __shared__ int carry;
  int tid = threadIdx.x;
  int lane = tid & 63, wid = tid >> 6;
  if (tid == 0) { carry = 0; rp[0] = 0; }
  __syncthreads();
  for (int base = 0; base < n; base += 1024) {
    int i = base + tid;
    int v = (i < n) ? cnt[i] : 0;
    int s = v;
    #pragma unroll
    for (int o = 1; o < 64; o <<= 1) {
      int t = __shfl_up(s, o, 64);
      if (lane >= o) s += t;
    }
    if (lane == 63) wsum[wid] = s;
    __syncthreads();
    if (wid == 0) {
      int x = (lane < 16) ? wsum[lane] : 0;
      #pragma unroll
      for (int o = 1; o < 16; o <<= 1) {
        int t = __shfl_up(x, o, 64);
        if (lane >= o) x += t;
      }
      if (lane < 16) wsum[lane] = x;
    }
    __syncthreads();
    int off = carry + (wid > 0 ? wsum[wid - 1] : 0);
    if (i < n) rp[i + 1] = off + s;
    __syncthreads();
    if (tid == 0) carry += wsum[15];
    __syncthreads();
  }
}

__global__ void scatter_kernel(const int* __restrict__ src, const int* __restrict__ dst, int E,
                               int* __restrict__ cursor, int* __restrict__ outidx) {
  int i = blockIdx.x * 256 + threadIdx.x;
  if (i < E) {
    int p = atomicAdd(&cursor[dst[i]], 1);
    outidx[p] = src[i];
  }
}

// ---------------------------------------------------------------- encoders (h stored bf16)
__global__ void gather_lbl_kernel(const int* __restrict__ labels, const float* __restrict__ emb,
                                  unsigned short* __restrict__ h, int n) {
  int i = blockIdx.x * 256 + threadIdx.x;   // n*32 items, 4 floats each (128 cols)
  int node = i >> 5, l = i & 31;
  if (node < n) {
    float4 v = ((const float4*)(emb + (size_t)labels[node] * 128))[l];
    s16x4 o;
    o.x = (short)f2bf(v.x); o.y = (short)f2bf(v.y);
    o.z = (short)f2bf(v.z); o.w = (short)f2bf(v.w);
    *(s16x4*)(h + (size_t)node * 256 + l * 4) = o;
  }
}

__global__ void bcast_temb_kernel(const float* __restrict__ t, unsigned short* __restrict__ h) {
  int i = blockIdx.x * 256 + threadIdx.x;   // N_TEST*64, 4 each
  int node = i >> 6, l = i & 63;
  if (node < N_TEST) {
    float4 v = ((const float4*)t)[l];
    s16x4 o;
    o.x = (short)f2bf(v.x); o.y = (short)f2bf(v.y);
    o.z = (short)f2bf(v.z); o.w = (short)f2bf(v.w);
    *(s16x4*)(h + (size_t)node * 256 + l * 4) = o;
  }
}

// c_content[M,300] @ W[300,128] + b -> h[row*256 + 128 + col]  (fp32 math, bf16 out)
__global__ __launch_bounds__(256) void gemm_enc_kernel(
    const float* __restrict__ A, int M,
    const float* __restrict__ B, const float* __restrict__ bias,
    unsigned short* __restrict__ h) {
  __shared__ float As[16][132];
  __shared__ float Bs[16][132];
  int tid = threadIdx.x;
  int bm0 = blockIdx.x * 128;
  int ar = tid >> 2, ac4 = tid & 3;
  int bk = tid >> 5, bn4 = tid & 31;
  int tx = tid & 15, ty = tid >> 4;
  float acc[2][2][4][4];
  #pragma unroll
  for (int a = 0; a < 2; ++a)
    #pragma unroll
    for (int bq = 0; bq < 2; ++bq)
      #pragma unroll
      for (int j = 0; j < 4; ++j)
        #pragma unroll
        for (int i = 0; i < 4; ++i) acc[a][bq][j][i] = 0.f;

  const int KT = 19;
  for (int kt = 0; kt < KT; ++kt) {
    __syncthreads();
    int k0 = kt * 16;
    #pragma unroll
    for (int hh = 0; hh < 2; ++hh) {
      int row = bm0 + ar + hh * 64;
      int c = k0 + ac4 * 4;
      float4 av = make_float4(0.f, 0.f, 0.f, 0.f);
      if (row < M) {
        if (c + 3 < 300) {
          av = *(const float4*)(A + (size_t)row * 300 + c);
        } else {
          float* avp = &av.x;
          for (int j = 0; j < 4; ++j)
            if (c + j < 300) avp[j] = A[(size_t)row * 300 + c + j];
        }
      }
      As[ac4 * 4 + 0][ar + hh * 64] = av.x;
      As[ac4 * 4 + 1][ar + hh * 64] = av.y;
      As[ac4 * 4 + 2][ar + hh * 64] = av.z;
      As[ac4 * 4 + 3][ar + hh * 64] = av.w;
    }
    #pragma unroll
    for (int hh = 0; hh < 2; ++hh) {
      int kk = bk + hh * 8;
      int kg = k0 + kk;
      float4 bv = make_float4(0.f, 0.f, 0.f, 0.f);
      if (kg < 300) bv = *(const float4*)(B + (size_t)kg * 128 + bn4 * 4);
      *(float4*)&Bs[kk][bn4 * 4] = bv;
    }
    __syncthreads();
    #pragma unroll
    for (int kk = 0; kk < 16; ++kk) {
      float4 a0 = *(const float4*)&As[kk][ty * 4];
      float4 a1 = *(const float4*)&As[kk][64 + ty * 4];
      float4 b0 = *(const float4*)&Bs[kk][tx * 4];
      float4 b1 = *(const float4*)&Bs[kk][64 + tx * 4];
      const float av[2][4] = {{a0.x, a0.y, a0.z, a0.w}, {a1.x, a1.y, a1.z, a1.w}};
      const float bv[2][4] = {{b0.x, b0.y, b0.z, b0.w}, {b1.x, b1.y, b1.z, b1.w}};
      #pragma unroll
      for (int qm = 0; qm < 2; ++qm)
        #pragma unroll
        for (int j = 0; j < 4; ++j) {
          float a = av[qm][j];
          #pragma unroll
          for (int qn = 0; qn < 2; ++qn)
            #pragma unroll
            for (int i = 0; i < 4; ++i)
              acc[qm][qn][j][i] = fmaf(a, bv[qn][i], acc[qm][qn][j][i]);
        }
    }
  }
  #pragma unroll
  for (int qm = 0; qm < 2; ++qm)
    #pragma unroll
    for (int j = 0; j < 4; ++j) {
      int row = bm0 + qm * 64 + ty * 4 + j;
      if (row >= M) continue;
      #pragma unroll
      for (int qn = 0; qn < 2; ++qn) {
        int lc = qn * 64 + tx * 4;
        s16x4 o;
        o.x = (short)f2bf(acc[qm][qn][j][0] + bias[lc + 0]);
        o.y = (short)f2bf(acc[qm][qn][j][1] + bias[lc + 1]);
        o.z = (short)f2bf(acc[qm][qn][j][2] + bias[lc + 2]);
        o.w = (short)f2bf(acc[qm][qn][j][3] + bias[lc + 3]);
        *(s16x4*)(h + (size_t)row * 256 + 128 + lc) = o;
      }
    }
}

// ---------------------------------------------------------------- W -> bf16 transpose
// W_rel fp32 [5][6][K=256][N=256]  ->  Wt bf16 [5][6][N=256][K=256]
__global__ void wt_kernel(const float* __restrict__ W, unsigned short* __restrict__ Wt) {
  int i = blockIdx.x * 256 + threadIdx.x;
  int k = i & 255, n = (i >> 8) & 255, lr = i >> 16;
  Wt[i] = f2bf(W[((size_t)lr * 256 + k) * 256 + n]);
}

// ---------------------------------------------------------------- aggregation (bf16 h -> fp32 acc -> bf16 A)
__global__ void agg_bf16_kernel(const unsigned short* __restrict__ hsrc, const int* __restrict__ rp,
                                const int* __restrict__ si, unsigned short* __restrict__ A,
                                int strideK, int colOff, int n) {
  int w = (blockIdx.x * blockDim.x + threadIdx.x) >> 6;
  int lane = threadIdx.x & 63;
  if (w >= n) return;
  int b = rp[w], e = rp[w + 1];
  float a0 = 0.f, a1 = 0.f, a2 = 0.f, a3 = 0.f;
  for (int i = b; i < e; ++i) {
    s16x4 v = *(const s16x4*)(hsrc + (size_t)si[i] * 256 + lane * 4);
    a0 += bf2f((unsigned short)v.x); a1 += bf2f((unsigned short)v.y);
    a2 += bf2f((unsigned short)v.z); a3 += bf2f((unsigned short)v.w);
  }
  s16x4 o;
  o.x = (short)f2bf(a0); o.y = (short)f2bf(a1);
  o.z = (short)f2bf(a2); o.w = (short)f2bf(a3);
  *(s16x4*)(A + (size_t)w * strideK + colOff + lane * 4) = o;
}

// ---------------------------------------------------------------- MFMA layer GEMM
// out[row,0:256] = bf16( relu(A[row,0:K]@[W_r0;W_r1;W_r2] + sum b) (+residual) )
// Counted-vmcnt pipeline: raw s_barrier (no drain) + s_waitcnt vmcnt(8); never vmcnt(0) mid-loop.
__global__ __launch_bounds__(256) void gemm_mfma_kernel(
    const unsigned short* __restrict__ A, int M, int K,
    const unsigned short* __restrict__ Wt,
    const float* __restrict__ brel, int layer, int r0, int r1, int r2,
    const unsigned short* __restrict__ residual, unsigned short* __restrict__ out) {
  __shared__ __align__(16) unsigned short As[2][8192];   // [128 m][8 slots of 8 bf16] swizzled
  __shared__ __align__(16) unsigned short Bs[2][8192];   // [128 n][...] swizzled
  __shared__ float biasS[128];
  int tid = threadIdx.x, lane = tid & 63, wid = tid >> 6;

  // bijective chunked XCD swizzle (m204): pair (bx,0)/(bx,1) shares A-panel -> same XCD chunk
  int nwg = gridDim.x;
  int q = nwg >> 3, r = nwg & 7;
  int xcd = blockIdx.x & 7, idx = blockIdx.x >> 3;
  int wg = (xcd < r) ? (xcd * (q + 1) + idx) : (r * (q + 1) + (xcd - r) * q + idx);
  int gm0 = (wg >> 1) * 128;
  int n0  = (wg & 1) * 128;
  int rels[3] = {r0, r1, r2};

  if (tid < 128) {
    int col = n0 + tid;
    float s = brel[((size_t)layer * 6 + r0) * 256 + col];
    if (r1 >= 0) s += brel[((size_t)layer * 6 + r1) * 256 + col];
    if (r2 >= 0) s += brel[((size_t)layer * 6 + r2) * 256 + col];
    biasS[tid] = s;
  }

  int wr = wid >> 1, wc = wid & 1;
  f32x4 acc[4][4];
  #pragma unroll
  for (int mi = 0; mi < 4; ++mi)
    #pragma unroll
    for (int ni = 0; ni < 4; ++ni) acc[mi][ni] = (f32x4){0.f, 0.f, 0.f, 0.f};

  // stage 128x64 bf16 A+B tiles for K-step kt into buffer buf (8 gload_lds per wave).
  // LDS dest linear; XOR swizzle applied by permuting per-lane GLOBAL source.
  auto stage = [&](int buf, int kt) {
    int k0 = kt * 64;
    #pragma unroll
    for (int i = 0; i < 4; ++i) {
      int instr = wid * 4 + i;
      int P = instr * 64 + lane;
      int row = P >> 3, sp = P & 7;
      int s = sp ^ (row & 7);
      const unsigned short* g = A + (size_t)(gm0 + row) * K + k0 + s * 8;
      gload_lds16(g, &As[buf][instr * 512]);
    }
    #pragma unroll
    for (int i = 0; i < 4; ++i) {
      int instr = wid * 4 + i;
      int P = instr * 64 + lane;
      int row = P >> 3, sp = P & 7;
      int s = sp ^ (row & 7);
      const unsigned short* g = Wt + ((size_t)rels[k0 >> 8] * 256 + n0 + row) * 256
                                   + (k0 & 255) + s * 8;
      gload_lds16(g, &Bs[buf][instr * 512]);
    }
  };

  int nkt = K >> 6;       // >= 4 always
  stage(0, 0);
  stage(1, 1);
  asm volatile("s_waitcnt vmcnt(8)" ::: "memory");   // my buf0 loads landed
  __builtin_amdgcn_s_barrier();                      // everyone's buf0 loads landed

  for (int kt = 0; kt < nkt; ++kt) {
    int cur = kt & 1;
    #pragma unroll
    for (int kk = 0; kk < 2; ++kk) {
      bf16x8 af[4], bfr[4];
      int slBase = kk * 4 + (lane >> 4);
      #pragma unroll
      for (int mi = 0; mi < 4; ++mi) {
        int row = wr * 64 + mi * 16 + (lane & 15);
        af[mi] = *(const bf16x8*)&As[cur][row * 64 + ((slBase ^ (row & 7)) * 8)];
      }
      #pragma unroll
      for (int ni = 0; ni < 4; ++ni) {
        int row = wc * 64 + ni * 16 + (lane & 15);
        bfr[ni] = *(const bf16x8*)&Bs[cur][row * 64 + ((slBase ^ (row & 7)) * 8)];
      }
      __builtin_amdgcn_s_setprio(1);
      #pragma unroll
      for (int mi = 0; mi < 4; ++mi)
        #pragma unroll
        for (int ni = 0; ni < 4; ++ni)
          acc[mi][ni] = __builtin_amdgcn_mfma_f32_16x16x32_bf16(af[mi], bfr[ni], acc[mi][ni], 0, 0, 0);
      __builtin_amdgcn_s_setprio(0);
    }
    if (kt + 1 < nkt) {
      __builtin_amdgcn_s_barrier();                  // all waves done reading buffer cur
      if (kt + 2 < nkt) {
        stage(cur, kt + 2);                          // overwrite cur with tile kt+2
        asm volatile("s_waitcnt vmcnt(8)" ::: "memory");  // tile kt+1's loads (older) landed
      } else {
        asm volatile("s_waitcnt vmcnt(0)" ::: "memory");  // final tile: drain
      }
      __builtin_amdgcn_s_barrier();                  // next buffer ready for all waves
    }
  }

  #pragma unroll
  for (int mi = 0; mi < 4; ++mi)
    #pragma unroll
    for (int ni = 0; ni < 4; ++ni) {
      f32x4 v = acc[mi][ni];
      int coll = wc * 64 + ni * 16 + (lane & 15);
      int col = n0 + coll;
      #pragma unroll
      for (int j = 0; j < 4; ++j) {
        int row = gm0 + wr * 64 + mi * 16 + (lane >> 4) * 4 + j;
        if (row < M) {
          float x = fmaxf(v[j] + biasS[coll], 0.f);
          if (residual) x += bf2f(residual[(size_t)row * 256 + col]);
          out[(size_t)row * 256 + col] = f2bf(x);
        }
      }
    }
}

// ---------------------------------------------------------------- decoders (bf16 h in, fp32 out)
__global__ void decode2_kernel(const unsigned short* __restrict__ h, const float* __restrict__ W,
                               const float* __restrict__ b, float* __restrict__ logits,
                               float* __restrict__ soft, int n) {
  int w = (blockIdx.x * blockDim.x + threadIdx.x) >> 6;
  int lane = threadIdx.x & 63;
  if (w >= n) return;
  s16x4 hv = *(const s16x4*)(h + (size_t)w * 256 + lane * 4);
  float x0 = bf2f((unsigned short)hv.x), x1 = bf2f((unsigned short)hv.y);
  float x2 = bf2f((unsigned short)hv.z), x3 = bf2f((unsigned short)hv.w);
  int k = lane * 4;
  float l0 = x0 * W[(k + 0) * 2 + 0] + x1 * W[(k + 1) * 2 + 0] +
             x2 * W[(k + 2) * 2 + 0] + x3 * W[(k + 3) * 2 + 0];
  float l1 = x0 * W[(k + 0) * 2 + 1] + x1 * W[(k + 1) * 2 + 1] +
             x2 * W[(k + 2) * 2 + 1] + x3 * W[(k + 3) * 2 + 1];
  #pragma unroll
  for (int m = 1; m < 64; m <<= 1) {
    l0 += __shfl_xor(l0, m, 64);
    l1 += __shfl_xor(l1, m, 64);
  }
  if (lane == 0) {
    l0 += b[0]; l1 += b[1];
    float mx = fmaxf(l0, l1);
    float e0 = expf(l0 - mx), e1 = expf(l1 - mx);
    float s = e0 + e1;
    logits[(size_t)w * 2 + 0] = l0;
    logits[(size_t)w * 2 + 1] = l1;
    soft[(size_t)w * 2 + 0] = e0 / s;
    soft[(size_t)w * 2 + 1] = e1 / s;
  }
}

__global__ void decode3_kernel(const unsigned short* __restrict__ h, const float* __restrict__ W,
                               const float* __restrict__ b, float* __restrict__ logits,
                               float* __restrict__ soft, int n) {
  int w = (blockIdx.x * blockDim.x + threadIdx.x) >> 6;
  int lane = threadIdx.x & 63;
  if (w >= n) return;
  s16x4 hv = *(const s16x4*)(h + (size_t)w * 256 + lane * 4);
  float x0 = bf2f((unsigned short)hv.x), x1 = bf2f((unsigned short)hv.y);
  float x2 = bf2f((unsigned short)hv.z), x3 = bf2f((unsigned short)hv.w);
  int k = lane * 4;
  float l0 = x0 * W[(k + 0) * 3 + 0] + x1 * W[(k + 1) * 3 + 0] +
             x2 * W[(k + 2) * 3 + 0] + x3 * W[(k + 3) * 3 + 0];
  float l1 = x0 * W[(k + 0) * 3 + 1] + x1 * W[(k + 1) * 3 + 1] +
             x2 * W[(k + 2) * 3 + 1] + x3 * W[(k + 3) * 3 + 1];
  float l2 = x0 * W[(k + 0) * 3 + 2] + x1 * W[(k + 1) * 3 + 2] +
             x2 * W[(k + 2) * 3 + 2] + x3 * W[(k + 3) * 3 + 2];
  #pragma unroll
  for (int m = 1; m < 64; m <<= 1) {
    l0 += __shfl_xor(l0, m, 64);
    l1 += __shfl_xor(l1, m, 64);
    l2 += __shfl_xor(l2, m, 64);
  }
  if (lane == 0) {
    l0 += b[0]; l1 += b[1]; l2 += b[2];
    float mx = fmaxf(fmaxf(l0, l1), l2);
    float e0 = expf(l0 - mx), e1 = expf(l1 - mx), e2 = expf(l2 - mx);
    float s = e0 + e1 + e2;
    logits[(size_t)w * 3 + 0] = l0;
    logits[(size_t)w * 3 + 1] = l1;
    logits[(size_t)w * 3 + 2] = l2;
    soft[(size_t)w * 3 + 0] = e0 / s;
    soft[(size_t)w * 3 + 1] = e1 / s;
    soft[(size_t)w * 3 + 2] = e2 / s;
  }
}

// ---------------------------------------------------------------- host
extern "C" void kernel_launch(void* const* d_in, const int* in_sizes, int n_in,
                              void* d_out, int out_size, void* d_ws, size_t ws_size,
                              hipStream_t stream) {
  (void)in_sizes; (void)n_in; (void)out_size; (void)ws_size;
  const int*   c_labels  = (const int*)  d_in[0];
  const float* c_content = (const float*)d_in[1];
  const int*   a_labels  = (const int*)  d_in[2];
  const float* a_content = (const float*)d_in[3];
  const int*   edges[6];
  for (int r = 0; r < 6; ++r) edges[r] = (const int*)d_in[4 + r];
  const float* c_lbl_emb = (const float*)d_in[10];
  const float* c_enc_W   = (const float*)d_in[11];
  const float* c_enc_b   = (const float*)d_in[12];
  const float* a_lbl_emb = (const float*)d_in[13];
  const float* a_enc_W   = (const float*)d_in[14];
  const float* a_enc_b   = (const float*)d_in[15];
  const float* t_emb     = (const float*)d_in[16];
  const float* W_rel     = (const float*)d_in[17];
  const float* b_rel     = (const float*)d_in[18];
  const float* dec_W     = (const float*)d_in[19];
  const float* dec_b     = (const float*)d_in[20];
  const float* adec_W    = (const float*)d_in[21];
  const float* adec_b    = (const float*)d_in[22];
  float* out = (float*)d_out;

  static const int E_CNT[6]    = {200000, 400000, 200000, 200000, 50000, 50000};
  static const int REL_DSTN[6] = {N_CFG, N_AST, N_CFG, N_AST, N_TEST, N_CFG};

  char* ws = (char*)d_ws;
  size_t off = 0;
  auto alloc = [&](size_t bytes) -> void* {
    void* p = ws + off;
    off += (bytes + 255) & ~(size_t)255;
    return p;
  };
  unsigned short* buf0 = (unsigned short*)alloc((size_t)NNODE * 256 * 2);
  unsigned short* buf1 = (unsigned short*)alloc((size_t)NNODE * 256 * 2);
  // bf16 A scratch; rows rounded up to 128 so MFMA tile tails read in-bounds
  unsigned short* Abuf = (unsigned short*)alloc((size_t)200064 * 512 * 2);
  unsigned short* Wt   = (unsigned short*)alloc((size_t)5 * 6 * 256 * 256 * 2);
  int* rowptr[6];
  int* srcidx[6];
  for (int r = 0; r < 6; ++r) rowptr[r] = (int*)alloc((size_t)(REL_DSTN[r] + 1) * 4);
  for (int r = 0; r < 6; ++r) srcidx[r] = (int*)alloc((size_t)E_CNT[r] * 4);
  int* cursor = (int*)alloc((size_t)(N_AST + 1) * 4);

  // weights -> bf16 transposed [l][r][n][k]
  wt_kernel<<<CDIV(5 * 6 * 256 * 256, 256), 256, 0, stream>>>(W_rel, Wt);

  // CSR (dst-sorted) per relation
  for (int r = 0; r < 6; ++r) {
    int nd = REL_DSTN[r], E = E_CNT[r];
    const int* esrc = edges[r];
    const int* edst = edges[r] + E;
    zero_int_kernel<<<CDIV(nd, 256), 256, 0, stream>>>(cursor, nd);
    hist_kernel<<<CDIV(E, 256), 256, 0, stream>>>(edst, E, cursor);
    scan_kernel<<<1, 1024, 0, stream>>>(cursor, rowptr[r], nd);
    copy_int_kernel<<<CDIV(nd, 256), 256, 0, stream>>>(cursor, rowptr[r], nd);
    scatter_kernel<<<CDIV(E, 256), 256, 0, stream>>>(esrc, edst, E, cursor, srcidx[r]);
  }

  const size_t OFF_CFG = 0;
  const size_t OFF_AST = (size_t)N_CFG * 256;
  const size_t OFF_TST = (size_t)(N_CFG + N_AST) * 256;

  // encoders -> buf0 (bf16)
  gather_lbl_kernel<<<CDIV(N_CFG * 32, 256), 256, 0, stream>>>(c_labels, c_lbl_emb, buf0 + OFF_CFG, N_CFG);
  gather_lbl_kernel<<<CDIV(N_AST * 32, 256), 256, 0, stream>>>(a_labels, a_lbl_emb, buf0 + OFF_AST, N_AST);
  gemm_enc_kernel<<<dim3(CDIV(N_CFG, 128), 1), 256, 0, stream>>>(c_content, N_CFG, c_enc_W, c_enc_b, buf0 + OFF_CFG);
  gemm_enc_kernel<<<dim3(CDIV(N_AST, 128), 1), 256, 0, stream>>>(a_content, N_AST, a_enc_W, a_enc_b, buf0 + OFF_AST);
  bcast_temb_kernel<<<CDIV(N_TEST * 64, 256), 256, 0, stream>>>(t_emb, buf0 + OFF_TST);

  unsigned short* h_in = buf0;
  unsigned short* h_out = buf1;
  for (int l = 0; l < 5; ++l) {
    bool use_res = (l == 1 || l == 3);
    const unsigned short* WtL = Wt + (size_t)l * 6 * 256 * 256;
    // dst cfg: rels 0(cc), 2(ac), 5(tc); K = 768
    agg_bf16_kernel<<<CDIV(N_CFG, 4), 256, 0, stream>>>(h_in + OFF_CFG, rowptr[0], srcidx[0], Abuf, 768, 0,   N_CFG);
    agg_bf16_kernel<<<CDIV(N_CFG, 4), 256, 0, stream>>>(h_in + OFF_AST, rowptr[2], srcidx[2], Abuf, 768, 256, N_CFG);
    agg_bf16_kernel<<<CDIV(N_CFG, 4), 256, 0, stream>>>(h_in + OFF_TST, rowptr[5], srcidx[5], Abuf, 768, 512, N_CFG);
    gemm_mfma_kernel<<<CDIV(N_CFG, 128) * 2, 256, 0, stream>>>(
        Abuf, N_CFG, 768, WtL, b_rel, l, 0, 2, 5,
        use_res ? h_in + OFF_CFG : nullptr, h_out + OFF_CFG);
    // dst ast: rels 1(aa), 3(ca); K = 512
    agg_bf16_kernel<<<CDIV(N_AST, 4), 256, 0, stream>>>(h_in + OFF_AST, rowptr[1], srcidx[1], Abuf, 512, 0,   N_AST);
    agg_bf16_kernel<<<CDIV(N_AST, 4), 256, 0, stream>>>(h_in + OFF_CFG, rowptr[3], srcidx[3], Abuf, 512, 256, N_AST);
    gemm_mfma_kernel<<<CDIV(N_AST, 128) * 2, 256, 0, stream>>>(
        Abuf, N_AST, 512, WtL, b_rel, l, 1, 3, -1,
        use_res ? h_in + OFF_AST : nullptr, h_out + OFF_AST);
    // dst test: rel 4(ct); K = 256
    agg_bf16_kernel<<<CDIV(N_TEST, 4), 256, 0, stream>>>(h_in + OFF_CFG, rowptr[4], srcidx[4], Abuf, 256, 0, N_TEST);
    gemm_mfma_kernel<<<CDIV(N_TEST, 128) * 2, 256, 0, stream>>>(
        Abuf, N_TEST, 256, WtL, b_rel, l, 4, -1, -1,
        use_res ? h_in + OFF_TST : nullptr, h_out + OFF_TST);
    unsigned short* t = h_in; h_in = h_out; h_out = t;
  }

  decode2_kernel<<<CDIV(N_CFG, 4), 256, 0, stream>>>(h_in + OFF_CFG, dec_W, dec_b,
                                                     out, out + 100000, N_CFG);
  decode3_kernel<<<CDIV(N_AST, 4), 256, 0, stream>>>(h_in + OFF_AST, adec_W, adec_b,
                                                     out + 200000, out + 800000, N_AST);
}

// Round 4
// 3303.328 us; speedup vs baseline: 2.3295x; 1.1194x over previous
//
#include <hip/hip_runtime.h>
#include <stdint.h>
#include <stddef.h>

#define CDIV(a,b) (((a)+(b)-1)/(b))

#define N_CFG  50000
#define N_AST  200000
#define N_TEST 1000
#define NNODE  (N_CFG + N_AST + N_TEST)

typedef __attribute__((ext_vector_type(8))) short bf16x8;
typedef __attribute__((ext_vector_type(4))) short s16x4;
typedef __attribute__((ext_vector_type(4))) float f32x4;

__device__ __forceinline__ unsigned short f2bf(float f) {
  union { float f; unsigned int u; } x; x.f = f;
  unsigned int r = x.u + 0x7fffu + ((x.u >> 16) & 1u);   // RNE
  return (unsigned short)(r >> 16);
}
__device__ __forceinline__ float bf2f(unsigned short b) {
  union { unsigned int u; float f; } x; x.u = ((unsigned int)b) << 16;
  return x.f;
}

__device__ __forceinline__ void gload_lds16(const void* g, void* l) {
  __builtin_amdgcn_global_load_lds((const __attribute__((address_space(1))) unsigned int*)g,
                                   (__attribute__((address_space(3))) unsigned int*)l,
                                   16, 0, 0);
}

// ---------------------------------------------------------------- CSR build
__global__ void zero_int_kernel(int* __restrict__ p, int n) {
  int i = blockIdx.x * 256 + threadIdx.x;
  if (i < n) p[i] = 0;
}

__global__ void hist_kernel(const int* __restrict__ dst, int E, int* __restrict__ cnt) {
  int i = blockIdx.x * 256 + threadIdx.x;
  if (i < E) atomicAdd(&cnt[dst[i]], 1);
}

__global__ void copy_int_kernel(int* __restrict__ d, const int* __restrict__ s, int n) {
  int i = blockIdx.x * 256 + threadIdx.x;
  if (i < n) d[i] = s[i];
}

// single-block scan, 4 elems/thread (int4): rp[0]=0, rp[i+1]=sum cnt[0..i]
__global__ __launch_bounds__(1024) void scan_kernel(const int* __restrict__ cnt,
                                                    int* __restrict__ rp, int n) {
  __shared__ int wsum[16];
  __shared__ int carry;
  int tid = threadIdx.x;
  int lane = tid & 63, wid = tid >> 6;
  if (tid == 0) { carry = 0; rp[0] = 0; }
  __syncthreads();
  for (int base = 0; base < n; base += 4096) {
    int i0 = base + tid * 4;
    int4 v = make_int4(0, 0, 0, 0);
    if (i0 + 3 < n) {
      v = *(const int4*)(cnt + i0);
    } else if (i0 < n) {
      v.x = cnt[i0];
      if (i0 + 1 < n) v.y = cnt[i0 + 1];
      if (i0 + 2 < n) v.z = cnt[i0 + 2];
    }
    int s1 = v.x + v.y, s2 = s1 + v.z, s3 = s2 + v.w;
    int s = s3;
    #pragma unroll
    for (int o = 1; o < 64; o <<= 1) {
      int t = __shfl_up(s, o, 64);
      if (lane >= o) s += t;
    }
    if (lane == 63) wsum[wid] = s;
    __syncthreads();
    if (wid == 0) {
      int x = (lane < 16) ? wsum[lane] : 0;
      #pragma unroll
      for (int o = 1; o < 16; o <<= 1) {
        int t = __shfl_up(x, o, 64);
        if (lane >= o) x += t;
      }
      if (lane < 16) wsum[lane] = x;
    }
    __syncthreads();
    int off = carry + (wid > 0 ? wsum[wid - 1] : 0) + (s - s3);
    if (i0 < n)     rp[i0 + 1] = off + v.x;
    if (i0 + 1 < n) rp[i0 + 2] = off + s1;
    if (i0 + 2 < n) rp[i0 + 3] = off + s2;
    if (i0 + 3 < n) rp[i0 + 4] = off + s3;
    __syncthreads();
    if (tid == 0) carry += wsum[15];
    __syncthreads();
  }
}

__global__ void scatter_kernel(const int* __restrict__ src, const int* __restrict__ dst, int E,
                               int* __restrict__ cursor, int* __restrict__ outidx) {
  int i = blockIdx.x * 256 + threadIdx.x;
  if (i < E) {
    int p = atomicAdd(&cursor[dst[i]], 1);
    outidx[p] = src[i];
  }
}

// ---------------------------------------------------------------- encoders (h stored bf16)
__global__ void gather_lbl_kernel(const int* __restrict__ labels, const float* __restrict__ emb,
                                  unsigned short* __restrict__ h, int n) {
  int i = blockIdx.x * 256 + threadIdx.x;   // n*32 items, 4 floats each (128 cols)
  int node = i >> 5, l = i & 31;
  if (node < n) {
    float4 v = ((const float4*)(emb + (size_t)labels[node] * 128))[l];
    s16x4 o;
    o.x = (short)f2bf(v.x); o.y = (short)f2bf(v.y);
    o.z = (short)f2bf(v.z); o.w = (short)f2bf(v.w);
    *(s16x4*)(h + (size_t)node * 256 + l * 4) = o;
  }
}

__global__ void bcast_temb_kernel(const float* __restrict__ t, unsigned short* __restrict__ h) {
  int i = blockIdx.x * 256 + threadIdx.x;   // N_TEST*64, 4 each
  int node = i >> 6, l = i & 63;
  if (node < N_TEST) {
    float4 v = ((const float4*)t)[l];
    s16x4 o;
    o.x = (short)f2bf(v.x); o.y = (short)f2bf(v.y);
    o.z = (short)f2bf(v.z); o.w = (short)f2bf(v.w);
    *(s16x4*)(h + (size_t)node * 256 + l * 4) = o;
  }
}

// enc W fp32 [300][128] -> bf16 [128 n][320 k] zero-padded (k >= 300 -> 0)
__global__ void wtenc_kernel(const float* __restrict__ W, unsigned short* __restrict__ Wt) {
  int i = blockIdx.x * 256 + threadIdx.x;   // over 128*320
  if (i >= 128 * 320) return;
  int k = i % 320, n = i / 320;
  Wt[i] = (k < 300) ? f2bf(W[(size_t)k * 128 + n]) : (unsigned short)0;
}

// content[M,300] @ W[300,128] + b -> bf16 h[row*256 + 128 + col]
// MFMA, K padded to 320. A reg-staged fp32->bf16 (swizzled ds_write); B via gload_lds.
__global__ __launch_bounds__(256) void enc_mfma_kernel(
    const float* __restrict__ A, int M,
    const unsigned short* __restrict__ WtE,   // [128][320] bf16
    const float* __restrict__ bias,           // [128] fp32
    unsigned short* __restrict__ h) {
  __shared__ __align__(16) unsigned short As[2][8192];   // [128 m][8 slots of 8] swizzled
  __shared__ __align__(16) unsigned short Bs[2][8192];   // [128 n][...] swizzled
  __shared__ float biasS[128];
  int tid = threadIdx.x, lane = tid & 63, wid = tid >> 6;
  int gm0 = blockIdx.x * 128;
  if (tid < 128) biasS[tid] = bias[tid];

  int wr = wid >> 1, wc = wid & 1;
  f32x4 acc[4][4];
  #pragma unroll
  for (int mi = 0; mi < 4; ++mi)
    #pragma unroll
    for (int ni = 0; ni < 4; ++ni) acc[mi][ni] = (f32x4){0.f, 0.f, 0.f, 0.f};

  auto stageB = [&](int buf, int kt) {
    int k0 = kt * 64;
    #pragma unroll
    for (int i = 0; i < 4; ++i) {
      int instr = wid * 4 + i;
      int P = instr * 64 + lane;
      int row = P >> 3, sp = P & 7;
      int s = sp ^ (row & 7);
      gload_lds16(WtE + (size_t)row * 320 + k0 + s * 8, &Bs[buf][instr * 512]);
    }
  };
  auto stageA = [&](int buf, int kt) {
    int k0 = kt * 64;
    #pragma unroll
    for (int j = 0; j < 4; ++j) {
      int q = tid * 4 + j;                 // 0..1023 physical-ish id
      int row = q >> 3, s = q & 7;         // logical slot s of row
      int grow = gm0 + row;
      int k = k0 + s * 8;
      float v[8];
      if (grow < M && k + 8 <= 300) {
        float4 u0 = *(const float4*)(A + (size_t)grow * 300 + k);
        float4 u1 = *(const float4*)(A + (size_t)grow * 300 + k + 4);
        v[0] = u0.x; v[1] = u0.y; v[2] = u0.z; v[3] = u0.w;
        v[4] = u1.x; v[5] = u1.y; v[6] = u1.z; v[7] = u1.w;
      } else {
        #pragma unroll
        for (int e = 0; e < 8; ++e)
          v[e] = (grow < M && k + e < 300) ? A[(size_t)grow * 300 + k + e] : 0.f;
      }
      bf16x8 o;
      #pragma unroll
      for (int e = 0; e < 8; ++e) o[e] = (short)f2bf(v[e]);
      *(bf16x8*)&As[buf][row * 64 + ((s ^ (row & 7)) * 8)] = o;
    }
  };

  const int nkt = 5;   // 320 / 64
  stageA(0, 0); stageB(0, 0);
  __syncthreads();
  for (int kt = 0; kt < nkt; ++kt) {
    int cur = kt & 1;
    if (kt + 1 < nkt) { stageA(cur ^ 1, kt + 1); stageB(cur ^ 1, kt + 1); }
    #pragma unroll
    for (int kk = 0; kk < 2; ++kk) {
      bf16x8 af[4], bfr[4];
      int slBase = kk * 4 + (lane >> 4);
      #pragma unroll
      for (int mi = 0; mi < 4; ++mi) {
        int row = wr * 64 + mi * 16 + (lane & 15);
        af[mi] = *(const bf16x8*)&As[cur][row * 64 + ((slBase ^ (row & 7)) * 8)];
      }
      #pragma unroll
      for (int ni = 0; ni < 4; ++ni) {
        int row = wc * 64 + ni * 16 + (lane & 15);
        bfr[ni] = *(const bf16x8*)&Bs[cur][row * 64 + ((slBase ^ (row & 7)) * 8)];
      }
      __builtin_amdgcn_s_setprio(1);
      #pragma unroll
      for (int mi = 0; mi < 4; ++mi)
        #pragma unroll
        for (int ni = 0; ni < 4; ++ni)
          acc[mi][ni] = __builtin_amdgcn_mfma_f32_16x16x32_bf16(af[mi], bfr[ni], acc[mi][ni], 0, 0, 0);
      __builtin_amdgcn_s_setprio(0);
    }
    __syncthreads();
  }

  #pragma unroll
  for (int mi = 0; mi < 4; ++mi)
    #pragma unroll
    for (int ni = 0; ni < 4; ++ni) {
      f32x4 v = acc[mi][ni];
      int coll = wc * 64 + ni * 16 + (lane & 15);   // 0..127
      #pragma unroll
      for (int j = 0; j < 4; ++j) {
        int row = gm0 + wr * 64 + mi * 16 + (lane >> 4) * 4 + j;
        if (row < M)
          h[(size_t)row * 256 + 128 + coll] = f2bf(v[j] + biasS[coll]);
      }
    }
}

// ---------------------------------------------------------------- W -> bf16 transpose
// W_rel fp32 [5][6][K=256][N=256]  ->  Wt bf16 [5][6][N=256][K=256]
__global__ void wt_kernel(const float* __restrict__ W, unsigned short* __restrict__ Wt) {
  int i = blockIdx.x * 256 + threadIdx.x;
  int k = i & 255, n = (i >> 8) & 255, lr = i >> 16;
  Wt[i] = f2bf(W[((size_t)lr * 256 + k) * 256 + n]);
}

// ---------------------------------------------------------------- aggregation (bf16 h -> fp32 acc -> bf16 A)
__global__ void agg_bf16_kernel(const unsigned short* __restrict__ hsrc, const int* __restrict__ rp,
                                const int* __restrict__ si, unsigned short* __restrict__ A,
                                int strideK, int colOff, int n) {
  int w = (blockIdx.x * blockDim.x + threadIdx.x) >> 6;
  int lane = threadIdx.x & 63;
  if (w >= n) return;
  int b = rp[w], e = rp[w + 1];
  float a0 = 0.f, a1 = 0.f, a2 = 0.f, a3 = 0.f;
  for (int i = b; i < e; ++i) {
    s16x4 v = *(const s16x4*)(hsrc + (size_t)si[i] * 256 + lane * 4);
    a0 += bf2f((unsigned short)v.x); a1 += bf2f((unsigned short)v.y);
    a2 += bf2f((unsigned short)v.z); a3 += bf2f((unsigned short)v.w);
  }
  s16x4 o;
  o.x = (short)f2bf(a0); o.y = (short)f2bf(a1);
  o.z = (short)f2bf(a2); o.w = (short)f2bf(a3);
  *(s16x4*)(A + (size_t)w * strideK + colOff + lane * 4) = o;
}

// ---------------------------------------------------------------- MFMA layer GEMM
// out[row,0:256] = bf16( relu(A[row,0:K]@[W_r0;W_r1;W_r2] + sum b) (+residual) )
// Counted-vmcnt pipeline: raw s_barrier (no drain) + s_waitcnt vmcnt(8); never vmcnt(0) mid-loop.
__global__ __launch_bounds__(256) void gemm_mfma_kernel(
    const unsigned short* __restrict__ A, int M, int K,
    const unsigned short* __restrict__ Wt,
    const float* __restrict__ brel, int layer, int r0, int r1, int r2,
    const unsigned short* __restrict__ residual, unsigned short* __restrict__ out) {
  __shared__ __align__(16) unsigned short As[2][8192];   // [128 m][8 slots of 8 bf16] swizzled
  __shared__ __align__(16) unsigned short Bs[2][8192];   // [128 n][...] swizzled
  __shared__ float biasS[128];
  int tid = threadIdx.x, lane = tid & 63, wid = tid >> 6;

  // bijective chunked XCD swizzle (m204): pair (bx,0)/(bx,1) shares A-panel -> same XCD chunk
  int nwg = gridDim.x;
  int q = nwg >> 3, r = nwg & 7;
  int xcd = blockIdx.x & 7, idx = blockIdx.x >> 3;
  int wg = (xcd < r) ? (xcd * (q + 1) + idx) : (r * (q + 1) + (xcd - r) * q + idx);
  int gm0 = (wg >> 1) * 128;
  int n0  = (wg & 1) * 128;
  int rels[3] = {r0, r1, r2};

  if (tid < 128) {
    int col = n0 + tid;
    float s = brel[((size_t)layer * 6 + r0) * 256 + col];
    if (r1 >= 0) s += brel[((size_t)layer * 6 + r1) * 256 + col];
    if (r2 >= 0) s += brel[((size_t)layer * 6 + r2) * 256 + col];
    biasS[tid] = s;
  }

  int wr = wid >> 1, wc = wid & 1;
  f32x4 acc[4][4];
  #pragma unroll
  for (int mi = 0; mi < 4; ++mi)
    #pragma unroll
    for (int ni = 0; ni < 4; ++ni) acc[mi][ni] = (f32x4){0.f, 0.f, 0.f, 0.f};

  // stage 128x64 bf16 A+B tiles for K-step kt into buffer buf (8 gload_lds per wave).
  // LDS dest linear; XOR swizzle applied by permuting per-lane GLOBAL source.
  auto stage = [&](int buf, int kt) {
    int k0 = kt * 64;
    #pragma unroll
    for (int i = 0; i < 4; ++i) {
      int instr = wid * 4 + i;
      int P = instr * 64 + lane;
      int row = P >> 3, sp = P & 7;
      int s = sp ^ (row & 7);
      const unsigned short* g = A + (size_t)(gm0 + row) * K + k0 + s * 8;
      gload_lds16(g, &As[buf][instr * 512]);
    }
    #pragma unroll
    for (int i = 0; i < 4; ++i) {
      int instr = wid * 4 + i;
      int P = instr * 64 + lane;
      int row = P >> 3, sp = P & 7;
      int s = sp ^ (row & 7);
      const unsigned short* g = Wt + ((size_t)rels[k0 >> 8] * 256 + n0 + row) * 256
                                   + (k0 & 255) + s * 8;
      gload_lds16(g, &Bs[buf][instr * 512]);
    }
  };

  int nkt = K >> 6;       // >= 4 always
  stage(0, 0);
  stage(1, 1);
  asm volatile("s_waitcnt vmcnt(8)" ::: "memory");   // my buf0 loads landed
  __builtin_amdgcn_s_barrier();                      // everyone's buf0 loads landed

  for (int kt = 0; kt < nkt; ++kt) {
    int cur = kt & 1;
    #pragma unroll
    for (int kk = 0; kk < 2; ++kk) {
      bf16x8 af[4], bfr[4];
      int slBase = kk * 4 + (lane >> 4);
      #pragma unroll
      for (int mi = 0; mi < 4; ++mi) {
        int row = wr * 64 + mi * 16 + (lane & 15);
        af[mi] = *(const bf16x8*)&As[cur][row * 64 + ((slBase ^ (row & 7)) * 8)];
      }
      #pragma unroll
      for (int ni = 0; ni < 4; ++ni) {
        int row = wc * 64 + ni * 16 + (lane & 15);
        bfr[ni] = *(const bf16x8*)&Bs[cur][row * 64 + ((slBase ^ (row & 7)) * 8)];
      }
      __builtin_amdgcn_s_setprio(1);
      #pragma unroll
      for (int mi = 0; mi < 4; ++mi)
        #pragma unroll
        for (int ni = 0; ni < 4; ++ni)
          acc[mi][ni] = __builtin_amdgcn_mfma_f32_16x16x32_bf16(af[mi], bfr[ni], acc[mi][ni], 0, 0, 0);
      __builtin_amdgcn_s_setprio(0);
    }
    if (kt + 1 < nkt) {
      __builtin_amdgcn_s_barrier();                  // all waves done reading buffer cur
      if (kt + 2 < nkt) {
        stage(cur, kt + 2);                          // overwrite cur with tile kt+2
        asm volatile("s_waitcnt vmcnt(8)" ::: "memory");  // tile kt+1's loads (older) landed
      } else {
        asm volatile("s_waitcnt vmcnt(0)" ::: "memory");  // final tile: drain
      }
      __builtin_amdgcn_s_barrier();                  // next buffer ready for all waves
    }
  }

  #pragma unroll
  for (int mi = 0; mi < 4; ++mi)
    #pragma unroll
    for (int ni = 0; ni < 4; ++ni) {
      f32x4 v = acc[mi][ni];
      int coll = wc * 64 + ni * 16 + (lane & 15);
      int col = n0 + coll;
      #pragma unroll
      for (int j = 0; j < 4; ++j) {
        int row = gm0 + wr * 64 + mi * 16 + (lane >> 4) * 4 + j;
        if (row < M) {
          float x = fmaxf(v[j] + biasS[coll], 0.f);
          if (residual) x += bf2f(residual[(size_t)row * 256 + col]);
          out[(size_t)row * 256 + col] = f2bf(x);
        }
      }
    }
}

// ---------------------------------------------------------------- decoders (bf16 h in, fp32 out)
__global__ void decode2_kernel(const unsigned short* __restrict__ h, const float* __restrict__ W,
                               const float* __restrict__ b, float* __restrict__ logits,
                               float* __restrict__ soft, int n) {
  int w = (blockIdx.x * blockDim.x + threadIdx.x) >> 6;
  int lane = threadIdx.x & 63;
  if (w >= n) return;
  s16x4 hv = *(const s16x4*)(h + (size_t)w * 256 + lane * 4);
  float x0 = bf2f((unsigned short)hv.x), x1 = bf2f((unsigned short)hv.y);
  float x2 = bf2f((unsigned short)hv.z), x3 = bf2f((unsigned short)hv.w);
  int k = lane * 4;
  float l0 = x0 * W[(k + 0) * 2 + 0] + x1 * W[(k + 1) * 2 + 0] +
             x2 * W[(k + 2) * 2 + 0] + x3 * W[(k + 3) * 2 + 0];
  float l1 = x0 * W[(k + 0) * 2 + 1] + x1 * W[(k + 1) * 2 + 1] +
             x2 * W[(k + 2) * 2 + 1] + x3 * W[(k + 3) * 2 + 1];
  #pragma unroll
  for (int m = 1; m < 64; m <<= 1) {
    l0 += __shfl_xor(l0, m, 64);
    l1 += __shfl_xor(l1, m, 64);
  }
  if (lane == 0) {
    l0 += b[0]; l1 += b[1];
    float mx = fmaxf(l0, l1);
    float e0 = expf(l0 - mx), e1 = expf(l1 - mx);
    float s = e0 + e1;
    logits[(size_t)w * 2 + 0] = l0;
    logits[(size_t)w * 2 + 1] = l1;
    soft[(size_t)w * 2 + 0] = e0 / s;
    soft[(size_t)w * 2 + 1] = e1 / s;
  }
}

__global__ void decode3_kernel(const unsigned short* __restrict__ h, const float* __restrict__ W,
                               const float* __restrict__ b, float* __restrict__ logits,
                               float* __restrict__ soft, int n) {
  int w = (blockIdx.x * blockDim.x + threadIdx.x) >> 6;
  int lane = threadIdx.x & 63;
  if (w >= n) return;
  s16x4 hv = *(const s16x4*)(h + (size_t)w * 256 + lane * 4);
  float x0 = bf2f((unsigned short)hv.x), x1 = bf2f((unsigned short)hv.y);
  float x2 = bf2f((unsigned short)hv.z), x3 = bf2f((unsigned short)hv.w);
  int k = lane * 4;
  float l0 = x0 * W[(k + 0) * 3 + 0] + x1 * W[(k + 1) * 3 + 0] +
             x2 * W[(k + 2) * 3 + 0] + x3 * W[(k + 3) * 3 + 0];
  float l1 = x0 * W[(k + 0) * 3 + 1] + x1 * W[(k + 1) * 3 + 1] +
             x2 * W[(k + 2) * 3 + 1] + x3 * W[(k + 3) * 3 + 1];
  float l2 = x0 * W[(k + 0) * 3 + 2] + x1 * W[(k + 1) * 3 + 2] +
             x2 * W[(k + 2) * 3 + 2] + x3 * W[(k + 3) * 3 + 2];
  #pragma unroll
  for (int m = 1; m < 64; m <<= 1) {
    l0 += __shfl_xor(l0, m, 64);
    l1 += __shfl_xor(l1, m, 64);
    l2 += __shfl_xor(l2, m, 64);
  }
  if (lane == 0) {
    l0 += b[0]; l1 += b[1]; l2 += b[2];
    float mx = fmaxf(fmaxf(l0, l1), l2);
    float e0 = expf(l0 - mx), e1 = expf(l1 - mx), e2 = expf(l2 - mx);
    float s = e0 + e1 + e2;
    logits[(size_t)w * 3 + 0] = l0;
    logits[(size_t)w * 3 + 1] = l1;
    logits[(size_t)w * 3 + 2] = l2;
    soft[(size_t)w * 3 + 0] = e0 / s;
    soft[(size_t)w * 3 + 1] = e1 / s;
    soft[(size_t)w * 3 + 2] = e2 / s;
  }
}

// ---------------------------------------------------------------- host
extern "C" void kernel_launch(void* const* d_in, const int* in_sizes, int n_in,
                              void* d_out, int out_size, void* d_ws, size_t ws_size,
                              hipStream_t stream) {
  (void)in_sizes; (void)n_in; (void)out_size; (void)ws_size;
  const int*   c_labels  = (const int*)  d_in[0];
  const float* c_content = (const float*)d_in[1];
  const int*   a_labels  = (const int*)  d_in[2];
  const float* a_content = (const float*)d_in[3];
  const int*   edges[6];
  for (int r = 0; r < 6; ++r) edges[r] = (const int*)d_in[4 + r];
  const float* c_lbl_emb = (const float*)d_in[10];
  const float* c_enc_W   = (const float*)d_in[11];
  const float* c_enc_b   = (const float*)d_in[12];
  const float* a_lbl_emb = (const float*)d_in[13];
  const float* a_enc_W   = (const float*)d_in[14];
  const float* a_enc_b   = (const float*)d_in[15];
  const float* t_emb     = (const float*)d_in[16];
  const float* W_rel     = (const float*)d_in[17];
  const float* b_rel     = (const float*)d_in[18];
  const float* dec_W     = (const float*)d_in[19];
  const float* dec_b     = (const float*)d_in[20];
  const float* adec_W    = (const float*)d_in[21];
  const float* adec_b    = (const float*)d_in[22];
  float* out = (float*)d_out;

  static const int E_CNT[6]    = {200000, 400000, 200000, 200000, 50000, 50000};
  static const int REL_DSTN[6] = {N_CFG, N_AST, N_CFG, N_AST, N_TEST, N_CFG};

  char* ws = (char*)d_ws;
  size_t off = 0;
  auto alloc = [&](size_t bytes) -> void* {
    void* p = ws + off;
    off += (bytes + 255) & ~(size_t)255;
    return p;
  };
  unsigned short* buf0 = (unsigned short*)alloc((size_t)NNODE * 256 * 2);
  unsigned short* buf1 = (unsigned short*)alloc((size_t)NNODE * 256 * 2);
  // bf16 A scratch; rows rounded up to 128 so MFMA tile tails read in-bounds
  unsigned short* Abuf = (unsigned short*)alloc((size_t)200064 * 512 * 2);
  unsigned short* Wt   = (unsigned short*)alloc((size_t)5 * 6 * 256 * 256 * 2);
  unsigned short* WtEc = (unsigned short*)alloc((size_t)128 * 320 * 2);
  unsigned short* WtEa = (unsigned short*)alloc((size_t)128 * 320 * 2);
  int* rowptr[6];
  int* srcidx[6];
  for (int r = 0; r < 6; ++r) rowptr[r] = (int*)alloc((size_t)(REL_DSTN[r] + 1) * 4);
  for (int r = 0; r < 6; ++r) srcidx[r] = (int*)alloc((size_t)E_CNT[r] * 4);
  int* cursor = (int*)alloc((size_t)(N_AST + 1) * 4);

  // weights -> bf16: layer W transposed [l][r][n][k]; encoder W [n][320] padded
  wt_kernel<<<CDIV(5 * 6 * 256 * 256, 256), 256, 0, stream>>>(W_rel, Wt);
  wtenc_kernel<<<CDIV(128 * 320, 256), 256, 0, stream>>>(c_enc_W, WtEc);
  wtenc_kernel<<<CDIV(128 * 320, 256), 256, 0, stream>>>(a_enc_W, WtEa);

  // CSR (dst-sorted) per relation
  for (int r = 0; r < 6; ++r) {
    int nd = REL_DSTN[r], E = E_CNT[r];
    const int* esrc = edges[r];
    const int* edst = edges[r] + E;
    zero_int_kernel<<<CDIV(nd, 256), 256, 0, stream>>>(cursor, nd);
    hist_kernel<<<CDIV(E, 256), 256, 0, stream>>>(edst, E, cursor);
    scan_kernel<<<1, 1024, 0, stream>>>(cursor, rowptr[r], nd);
    copy_int_kernel<<<CDIV(nd, 256), 256, 0, stream>>>(cursor, rowptr[r], nd);
    scatter_kernel<<<CDIV(E, 256), 256, 0, stream>>>(esrc, edst, E, cursor, srcidx[r]);
  }

  const size_t OFF_CFG = 0;
  const size_t OFF_AST = (size_t)N_CFG * 256;
  const size_t OFF_TST = (size_t)(N_CFG + N_AST) * 256;

  // encoders -> buf0 (bf16)
  gather_lbl_kernel<<<CDIV(N_CFG * 32, 256), 256, 0, stream>>>(c_labels, c_lbl_emb, buf0 + OFF_CFG, N_CFG);
  gather_lbl_kernel<<<CDIV(N_AST * 32, 256), 256, 0, stream>>>(a_labels, a_lbl_emb, buf0 + OFF_AST, N_AST);
  enc_mfma_kernel<<<CDIV(N_CFG, 128), 256, 0, stream>>>(c_content, N_CFG, WtEc, c_enc_b, buf0 + OFF_CFG);
  enc_mfma_kernel<<<CDIV(N_AST, 128), 256, 0, stream>>>(a_content, N_AST, WtEa, a_enc_b, buf0 + OFF_AST);
  bcast_temb_kernel<<<CDIV(N_TEST * 64, 256), 256, 0, stream>>>(t_emb, buf0 + OFF_TST);

  unsigned short* h_in = buf0;
  unsigned short* h_out = buf1;
  for (int l = 0; l < 5; ++l) {
    bool use_res = (l == 1 || l == 3);
    const unsigned short* WtL = Wt + (size_t)l * 6 * 256 * 256;
    // dst cfg: rels 0(cc), 2(ac), 5(tc); K = 768
    agg_bf16_kernel<<<CDIV(N_CFG, 4), 256, 0, stream>>>(h_in + OFF_CFG, rowptr[0], srcidx[0], Abuf, 768, 0,   N_CFG);
    agg_bf16_kernel<<<CDIV(N_CFG, 4), 256, 0, stream>>>(h_in + OFF_AST, rowptr[2], srcidx[2], Abuf, 768, 256, N_CFG);
    agg_bf16_kernel<<<CDIV(N_CFG, 4), 256, 0, stream>>>(h_in + OFF_TST, rowptr[5], srcidx[5], Abuf, 768, 512, N_CFG);
    gemm_mfma_kernel<<<CDIV(N_CFG, 128) * 2, 256, 0, stream>>>(
        Abuf, N_CFG, 768, WtL, b_rel, l, 0, 2, 5,
        use_res ? h_in + OFF_CFG : nullptr, h_out + OFF_CFG);
    // dst ast: rels 1(aa), 3(ca); K = 512
    agg_bf16_kernel<<<CDIV(N_AST, 4), 256, 0, stream>>>(h_in + OFF_AST, rowptr[1], srcidx[1], Abuf, 512, 0,   N_AST);
    agg_bf16_kernel<<<CDIV(N_AST, 4), 256, 0, stream>>>(h_in + OFF_CFG, rowptr[3], srcidx[3], Abuf, 512, 256, N_AST);
    gemm_mfma_kernel<<<CDIV(N_AST, 128) * 2, 256, 0, stream>>>(
        Abuf, N_AST, 512, WtL, b_rel, l, 1, 3, -1,
        use_res ? h_in + OFF_AST : nullptr, h_out + OFF_AST);
    // dst test: rel 4(ct); K = 256
    agg_bf16_kernel<<<CDIV(N_TEST, 4), 256, 0, stream>>>(h_in + OFF_CFG, rowptr[4], srcidx[4], Abuf, 256, 0, N_TEST);
    gemm_mfma_kernel<<<CDIV(N_TEST, 128) * 2, 256, 0, stream>>>(
        Abuf, N_TEST, 256, WtL, b_rel, l, 4, -1, -1,
        use_res ? h_in + OFF_TST : nullptr, h_out + OFF_TST);
    unsigned short* t = h_in; h_in = h_out; h_out = t;
  }

  decode2_kernel<<<CDIV(N_CFG, 4), 256, 0, stream>>>(h_in + OFF_CFG, dec_W, dec_b,
                                                     out, out + 100000, N_CFG);
  decode3_kernel<<<CDIV(N_AST, 4), 256, 0, stream>>>(h_in + OFF_AST, adec_W, adec_b,
                                                     out + 200000, out + 800000, N_AST);
}

// Round 5
// 2683.873 us; speedup vs baseline: 2.8672x; 1.2308x over previous
//
#include <hip/hip_runtime.h>
#include <stdint.h>
#include <stddef.h>

#define CDIV(a,b) (((a)+(b)-1)/(b))

#define N_CFG  50000
#define N_AST  200000
#define N_TEST 1000
#define NNODE  (N_CFG + N_AST + N_TEST)

typedef __attribute__((ext_vector_type(8))) short bf16x8;
typedef __attribute__((ext_vector_type(4))) short s16x4;
typedef __attribute__((ext_vector_type(4))) float f32x4;

__device__ __forceinline__ unsigned short f2bf(float f) {
  union { float f; unsigned int u; } x; x.f = f;
  unsigned int r = x.u + 0x7fffu + ((x.u >> 16) & 1u);   // RNE
  return (unsigned short)(r >> 16);
}
__device__ __forceinline__ float bf2f(unsigned short b) {
  union { unsigned int u; float f; } x; x.u = ((unsigned int)b) << 16;
  return x.f;
}

__device__ __forceinline__ void gload_lds16(const void* g, void* l) {
  __builtin_amdgcn_global_load_lds((const __attribute__((address_space(1))) unsigned int*)g,
                                   (__attribute__((address_space(3))) unsigned int*)l,
                                   16, 0, 0);
}

// ---------------------------------------------------------------- CSR build
__global__ void zero_int_kernel(int* __restrict__ p, int n) {
  int i = blockIdx.x * 256 + threadIdx.x;
  if (i < n) p[i] = 0;
}

__global__ void hist_kernel(const int* __restrict__ dst, int E, int* __restrict__ cnt) {
  int i = blockIdx.x * 256 + threadIdx.x;
  if (i < E) atomicAdd(&cnt[dst[i]], 1);
}

__global__ void copy_int_kernel(int* __restrict__ d, const int* __restrict__ s, int n) {
  int i = blockIdx.x * 256 + threadIdx.x;
  if (i < n) d[i] = s[i];
}

// single-block scan, 4 elems/thread (int4): rp[0]=0, rp[i+1]=sum cnt[0..i]
__global__ __launch_bounds__(1024) void scan_kernel(const int* __restrict__ cnt,
                                                    int* __restrict__ rp, int n) {
  __shared__ int wsum[16];
  __shared__ int carry;
  int tid = threadIdx.x;
  int lane = tid & 63, wid = tid >> 6;
  if (tid == 0) { carry = 0; rp[0] = 0; }
  __syncthreads();
  for (int base = 0; base < n; base += 4096) {
    int i0 = base + tid * 4;
    int4 v = make_int4(0, 0, 0, 0);
    if (i0 + 3 < n) {
      v = *(const int4*)(cnt + i0);
    } else if (i0 < n) {
      v.x = cnt[i0];
      if (i0 + 1 < n) v.y = cnt[i0 + 1];
      if (i0 + 2 < n) v.z = cnt[i0 + 2];
    }
    int s1 = v.x + v.y, s2 = s1 + v.z, s3 = s2 + v.w;
    int s = s3;
    #pragma unroll
    for (int o = 1; o < 64; o <<= 1) {
      int t = __shfl_up(s, o, 64);
      if (lane >= o) s += t;
    }
    if (lane == 63) wsum[wid] = s;
    __syncthreads();
    if (wid == 0) {
      int x = (lane < 16) ? wsum[lane] : 0;
      #pragma unroll
      for (int o = 1; o < 16; o <<= 1) {
        int t = __shfl_up(x, o, 64);
        if (lane >= o) x += t;
      }
      if (lane < 16) wsum[lane] = x;
    }
    __syncthreads();
    int off = carry + (wid > 0 ? wsum[wid - 1] : 0) + (s - s3);
    if (i0 < n)     rp[i0 + 1] = off + v.x;
    if (i0 + 1 < n) rp[i0 + 2] = off + s1;
    if (i0 + 2 < n) rp[i0 + 3] = off + s2;
    if (i0 + 3 < n) rp[i0 + 4] = off + s3;
    __syncthreads();
    if (tid == 0) carry += wsum[15];
    __syncthreads();
  }
}

__global__ void scatter_kernel(const int* __restrict__ src, const int* __restrict__ dst, int E,
                               int* __restrict__ cursor, int* __restrict__ outidx) {
  int i = blockIdx.x * 256 + threadIdx.x;
  if (i < E) {
    int p = atomicAdd(&cursor[dst[i]], 1);
    outidx[p] = src[i];
  }
}

// ---------------------------------------------------------------- encoders (h stored bf16)
__global__ void gather_lbl_kernel(const int* __restrict__ labels, const float* __restrict__ emb,
                                  unsigned short* __restrict__ h, int n) {
  int i = blockIdx.x * 256 + threadIdx.x;
  int node = i >> 5, l = i & 31;
  if (node < n) {
    float4 v = ((const float4*)(emb + (size_t)labels[node] * 128))[l];
    s16x4 o;
    o.x = (short)f2bf(v.x); o.y = (short)f2bf(v.y);
    o.z = (short)f2bf(v.z); o.w = (short)f2bf(v.w);
    *(s16x4*)(h + (size_t)node * 256 + l * 4) = o;
  }
}

__global__ void bcast_temb_kernel(const float* __restrict__ t, unsigned short* __restrict__ h) {
  int i = blockIdx.x * 256 + threadIdx.x;
  int node = i >> 6, l = i & 63;
  if (node < N_TEST) {
    float4 v = ((const float4*)t)[l];
    s16x4 o;
    o.x = (short)f2bf(v.x); o.y = (short)f2bf(v.y);
    o.z = (short)f2bf(v.z); o.w = (short)f2bf(v.w);
    *(s16x4*)(h + (size_t)node * 256 + l * 4) = o;
  }
}

// enc W fp32 [300][128] -> bf16 [128 n][320 k] zero-padded
__global__ void wtenc_kernel(const float* __restrict__ W, unsigned short* __restrict__ Wt) {
  int i = blockIdx.x * 256 + threadIdx.x;
  if (i >= 128 * 320) return;
  int k = i % 320, n = i / 320;
  Wt[i] = (k < 300) ? f2bf(W[(size_t)k * 128 + n]) : (unsigned short)0;
}

// content[M,300] @ W[300,128] + b -> bf16 h[row*256 + 128 + col]
__global__ __launch_bounds__(256) void enc_mfma_kernel(
    const float* __restrict__ A, int M,
    const unsigned short* __restrict__ WtE,   // [128][320] bf16
    const float* __restrict__ bias,           // [128] fp32
    unsigned short* __restrict__ h) {
  __shared__ __align__(16) unsigned short As[2][8192];
  __shared__ __align__(16) unsigned short Bs[2][8192];
  int tid = threadIdx.x, lane = tid & 63, wid = tid >> 6;
  int gm0 = blockIdx.x * 128;

  int wr = wid >> 1, wc = wid & 1;
  f32x4 acc[4][4];
  #pragma unroll
  for (int mi = 0; mi < 4; ++mi)
    #pragma unroll
    for (int ni = 0; ni < 4; ++ni) acc[mi][ni] = (f32x4){0.f, 0.f, 0.f, 0.f};

  auto stageB = [&](int buf, int kt) {
    int k0 = kt * 64;
    #pragma unroll
    for (int i = 0; i < 4; ++i) {
      int instr = wid * 4 + i;
      int P = instr * 64 + lane;
      int row = P >> 3, sp = P & 7;
      int s = sp ^ (row & 7);
      gload_lds16(WtE + (size_t)row * 320 + k0 + s * 8, &Bs[buf][instr * 512]);
    }
  };
  auto stageA = [&](int buf, int kt) {
    int k0 = kt * 64;
    #pragma unroll
    for (int j = 0; j < 4; ++j) {
      int q = tid * 4 + j;
      int row = q >> 3, s = q & 7;
      int grow = gm0 + row;
      int k = k0 + s * 8;
      float v[8];
      if (grow < M && k + 8 <= 300) {
        float4 u0 = *(const float4*)(A + (size_t)grow * 300 + k);
        float4 u1 = *(const float4*)(A + (size_t)grow * 300 + k + 4);
        v[0] = u0.x; v[1] = u0.y; v[2] = u0.z; v[3] = u0.w;
        v[4] = u1.x; v[5] = u1.y; v[6] = u1.z; v[7] = u1.w;
      } else {
        #pragma unroll
        for (int e = 0; e < 8; ++e)
          v[e] = (grow < M && k + e < 300) ? A[(size_t)grow * 300 + k + e] : 0.f;
      }
      bf16x8 o;
      #pragma unroll
      for (int e = 0; e < 8; ++e) o[e] = (short)f2bf(v[e]);
      *(bf16x8*)&As[buf][row * 64 + ((s ^ (row & 7)) * 8)] = o;
    }
  };

  const int nkt = 5;   // 320 / 64
  stageA(0, 0); stageB(0, 0);
  __syncthreads();
  for (int kt = 0; kt < nkt; ++kt) {
    int cur = kt & 1;
    if (kt + 1 < nkt) { stageA(cur ^ 1, kt + 1); stageB(cur ^ 1, kt + 1); }
    #pragma unroll
    for (int kk = 0; kk < 2; ++kk) {
      bf16x8 af[4], bfr[4];
      int slBase = kk * 4 + (lane >> 4);
      #pragma unroll
      for (int mi = 0; mi < 4; ++mi) {
        int row = wr * 64 + mi * 16 + (lane & 15);
        af[mi] = *(const bf16x8*)&As[cur][row * 64 + ((slBase ^ (row & 7)) * 8)];
      }
      #pragma unroll
      for (int ni = 0; ni < 4; ++ni) {
        int row = wc * 64 + ni * 16 + (lane & 15);
        bfr[ni] = *(const bf16x8*)&Bs[cur][row * 64 + ((slBase ^ (row & 7)) * 8)];
      }
      __builtin_amdgcn_s_setprio(1);
      #pragma unroll
      for (int mi = 0; mi < 4; ++mi)
        #pragma unroll
        for (int ni = 0; ni < 4; ++ni)
          acc[mi][ni] = __builtin_amdgcn_mfma_f32_16x16x32_bf16(bfr[ni], af[mi], acc[mi][ni], 0, 0, 0);
      __builtin_amdgcn_s_setprio(0);
    }
    __syncthreads();
  }

  // swapped layout: lane holds 4 consecutive cols for one row
  float4 b4[4];
  #pragma unroll
  for (int ni = 0; ni < 4; ++ni)
    b4[ni] = *(const float4*)(bias + wc * 64 + ni * 16 + (lane >> 4) * 4);
  #pragma unroll
  for (int mi = 0; mi < 4; ++mi) {
    int m = gm0 + wr * 64 + mi * 16 + (lane & 15);
    if (m >= M) continue;
    #pragma unroll
    for (int ni = 0; ni < 4; ++ni) {
      f32x4 v = acc[mi][ni];
      int nb = wc * 64 + ni * 16 + (lane >> 4) * 4;
      s16x4 o;
      o.x = (short)f2bf(v[0] + b4[ni].x);
      o.y = (short)f2bf(v[1] + b4[ni].y);
      o.z = (short)f2bf(v[2] + b4[ni].z);
      o.w = (short)f2bf(v[3] + b4[ni].w);
      *(s16x4*)(h + (size_t)m * 256 + 128 + nb) = o;
    }
  }
}

// ---------------------------------------------------------------- W -> bf16 transpose
// W_rel fp32 [5][6][K=256][N=256]  ->  Wt bf16 [5][6][N=256][K=256]
__global__ void wt_kernel(const float* __restrict__ W, unsigned short* __restrict__ Wt) {
  int i = blockIdx.x * 256 + threadIdx.x;
  int k = i & 255, n = (i >> 8) & 255, lr = i >> 16;
  Wt[i] = f2bf(W[((size_t)lr * 256 + k) * 256 + n]);
}

// summed bias per (layer, dst-type): bsum[l][dt][256]
__global__ void bsum_kernel(const float* __restrict__ brel, float* __restrict__ bsum) {
  int i = blockIdx.x * 256 + threadIdx.x;
  if (i >= 5 * 3 * 256) return;
  int n = i & 255, dt = (i >> 8) % 3, l = i / (3 * 256);
  float s;
  if (dt == 0)      s = brel[((size_t)l * 6 + 0) * 256 + n] + brel[((size_t)l * 6 + 2) * 256 + n] + brel[((size_t)l * 6 + 5) * 256 + n];
  else if (dt == 1) s = brel[((size_t)l * 6 + 1) * 256 + n] + brel[((size_t)l * 6 + 3) * 256 + n];
  else              s = brel[((size_t)l * 6 + 4) * 256 + n];
  bsum[i] = s;
}

// ---------------------------------------------------------------- fused aggregation (per dst type)
// wave per dst node; 2 half-waves process 2 edges concurrently (16B/lane), shfl_xor(32) reduce
__global__ void agg_fused_kernel(
    const unsigned short* __restrict__ h0, const int* __restrict__ rp0, const int* __restrict__ si0,
    const unsigned short* __restrict__ h1, const int* __restrict__ rp1, const int* __restrict__ si1,
    const unsigned short* __restrict__ h2, const int* __restrict__ rp2, const int* __restrict__ si2,
    int nrel, unsigned short* __restrict__ A, int strideK, int n) {
  int w = (blockIdx.x * blockDim.x + threadIdx.x) >> 6;
  int lane = threadIdx.x & 63;
  if (w >= n) return;
  int half = lane >> 5, l32 = lane & 31;
  auto do_rel = [&](const unsigned short* h, const int* rp, const int* si, int cOff) {
    int b = rp[w], e = rp[w + 1];
    float acc[8] = {0.f, 0.f, 0.f, 0.f, 0.f, 0.f, 0.f, 0.f};
    for (int i = b + half; i < e; i += 2) {
      bf16x8 v = *(const bf16x8*)(h + (size_t)si[i] * 256 + l32 * 8);
      #pragma unroll
      for (int k = 0; k < 8; ++k) acc[k] += bf2f((unsigned short)v[k]);
    }
    #pragma unroll
    for (int k = 0; k < 8; ++k) acc[k] += __shfl_xor(acc[k], 32, 64);
    if (half == 0) {
      bf16x8 o;
      #pragma unroll
      for (int k = 0; k < 8; ++k) o[k] = (short)f2bf(acc[k]);
      *(bf16x8*)(A + (size_t)w * strideK + cOff + l32 * 8) = o;
    }
  };
  do_rel(h0, rp0, si0, 0);
  if (nrel > 1) do_rel(h1, rp1, si1, 256);
  if (nrel > 2) do_rel(h2, rp2, si2, 512);
}

// ---------------------------------------------------------------- MFMA layer GEMM
// Depth-3 A / depth-2 B counted-vmcnt pipeline. LDS = 3*16K + 2*16K = 81920 B.
// Per step: compute(t); barrier; stageB(t+2); stageA(t+3); vmcnt(12); barrier.
// vmcnt(12) forces exactly {A(t+1), B(t+1)} complete (FIFO), leaving 12 newer in flight.
__global__ __launch_bounds__(256) void gemm_mfma_kernel(
    const unsigned short* __restrict__ A, int M, int K,
    const unsigned short* __restrict__ Wt,
    const float* __restrict__ bsum,          // [256] summed bias, this (layer,dsttype)
    int r0, int r1, int r2,
    const unsigned short* __restrict__ residual, unsigned short* __restrict__ out) {
  __shared__ __align__(16) unsigned short AsL[3][8192];
  __shared__ __align__(16) unsigned short BsL[2][8192];
  int tid = threadIdx.x, lane = tid & 63, wid = tid >> 6;

  // bijective chunked XCD swizzle: pair (bx,0)/(bx,1) shares A-panel -> same XCD chunk
  int nwg = gridDim.x;
  int q = nwg >> 3, r = nwg & 7;
  int xcd = blockIdx.x & 7, idx = blockIdx.x >> 3;
  int wg = (xcd < r) ? (xcd * (q + 1) + idx) : (r * (q + 1) + (xcd - r) * q + idx);
  int gm0 = (wg >> 1) * 128;
  int n0  = (wg & 1) * 128;
  int rels[3] = {r0, r1, r2};

  int wr = wid >> 1, wc = wid & 1;
  f32x4 acc[4][4];
  #pragma unroll
  for (int mi = 0; mi < 4; ++mi)
    #pragma unroll
    for (int ni = 0; ni < 4; ++ni) acc[mi][ni] = (f32x4){0.f, 0.f, 0.f, 0.f};

  int nkt = K >> 6;       // 4 / 8 / 12

  auto stageA = [&](int buf, int kt) {
    if (kt > nkt - 1) kt = nkt - 1;        // clamp: uniform vmcnt counting at tail
    int k0 = kt * 64;
    #pragma unroll
    for (int i = 0; i < 4; ++i) {
      int instr = wid * 4 + i;
      int P = instr * 64 + lane;
      int row = P >> 3, sp = P & 7;
      int s = sp ^ (row & 7);
      gload_lds16(A + (size_t)(gm0 + row) * K + k0 + s * 8, &AsL[buf][instr * 512]);
    }
  };
  auto stageB = [&](int buf, int kt) {
    if (kt > nkt - 1) kt = nkt - 1;
    int k0 = kt * 64;
    #pragma unroll
    for (int i = 0; i < 4; ++i) {
      int instr = wid * 4 + i;
      int P = instr * 64 + lane;
      int row = P >> 3, sp = P & 7;
      int s = sp ^ (row & 7);
      gload_lds16(Wt + ((size_t)rels[k0 >> 8] * 256 + n0 + row) * 256 + (k0 & 255) + s * 8,
                  &BsL[buf][instr * 512]);
    }
  };

  // prologue: A0 B0 A1 B1 A2 (20 ops); vmcnt(12) forces A0,B0, leaves A1,B1,A2
  stageA(0, 0); stageB(0, 0); stageA(1, 1); stageB(1, 1); stageA(2, 2);
  asm volatile("s_waitcnt vmcnt(12)" ::: "memory");
  __builtin_amdgcn_s_barrier();

  int a3 = 0, b2 = 0;
  for (int kt = 0; kt < nkt; ++kt) {
    #pragma unroll
    for (int kk = 0; kk < 2; ++kk) {
      bf16x8 af[4], bfr[4];
      int slBase = kk * 4 + (lane >> 4);
      #pragma unroll
      for (int mi = 0; mi < 4; ++mi) {
        int row = wr * 64 + mi * 16 + (lane & 15);
        af[mi] = *(const bf16x8*)&AsL[a3][row * 64 + ((slBase ^ (row & 7)) * 8)];
      }
      #pragma unroll
      for (int ni = 0; ni < 4; ++ni) {
        int row = wc * 64 + ni * 16 + (lane & 15);
        bfr[ni] = *(const bf16x8*)&BsL[b2][row * 64 + ((slBase ^ (row & 7)) * 8)];
      }
      __builtin_amdgcn_s_setprio(1);
      #pragma unroll
      for (int mi = 0; mi < 4; ++mi)
        #pragma unroll
        for (int ni = 0; ni < 4; ++ni)
          acc[mi][ni] = __builtin_amdgcn_mfma_f32_16x16x32_bf16(bfr[ni], af[mi], acc[mi][ni], 0, 0, 0);
      __builtin_amdgcn_s_setprio(0);
    }
    __builtin_amdgcn_s_barrier();          // all waves done reading AsL[a3], BsL[b2]
    stageB(b2, kt + 2);                    // B first (depth 2)
    stageA(a3, kt + 3);                    // then A (depth 3)
    asm volatile("s_waitcnt vmcnt(12)" ::: "memory");   // forces A(t+1), B(t+1) landed
    __builtin_amdgcn_s_barrier();
    a3 = (a3 == 2) ? 0 : a3 + 1;
    b2 ^= 1;
  }
  asm volatile("s_waitcnt vmcnt(0)" ::: "memory");      // drain clamped tail loads
  __builtin_amdgcn_sched_barrier(0);

  // epilogue (swapped layout: lane holds 4 consecutive cols of one row)
  float4 b4[4];
  #pragma unroll
  for (int ni = 0; ni < 4; ++ni)
    b4[ni] = *(const float4*)(bsum + n0 + wc * 64 + ni * 16 + (lane >> 4) * 4);
  #pragma unroll
  for (int mi = 0; mi < 4; ++mi) {
    int m = gm0 + wr * 64 + mi * 16 + (lane & 15);
    if (m >= M) continue;
    #pragma unroll
    for (int ni = 0; ni < 4; ++ni) {
      f32x4 v = acc[mi][ni];
      int nb = n0 + wc * 64 + ni * 16 + (lane >> 4) * 4;
      float x0 = fmaxf(v[0] + b4[ni].x, 0.f);
      float x1 = fmaxf(v[1] + b4[ni].y, 0.f);
      float x2 = fmaxf(v[2] + b4[ni].z, 0.f);
      float x3 = fmaxf(v[3] + b4[ni].w, 0.f);
      if (residual) {
        s16x4 rv = *(const s16x4*)(residual + (size_t)m * 256 + nb);
        x0 += bf2f((unsigned short)rv.x); x1 += bf2f((unsigned short)rv.y);
        x2 += bf2f((unsigned short)rv.z); x3 += bf2f((unsigned short)rv.w);
      }
      s16x4 o;
      o.x = (short)f2bf(x0); o.y = (short)f2bf(x1);
      o.z = (short)f2bf(x2); o.w = (short)f2bf(x3);
      *(s16x4*)(out + (size_t)m * 256 + nb) = o;
    }
  }
}

// ---------------------------------------------------------------- decoders (bf16 h in, fp32 out)
__global__ void decode2_kernel(const unsigned short* __restrict__ h, const float* __restrict__ W,
                               const float* __restrict__ b, float* __restrict__ logits,
                               float* __restrict__ soft, int n) {
  int w = (blockIdx.x * blockDim.x + threadIdx.x) >> 6;
  int lane = threadIdx.x & 63;
  if (w >= n) return;
  s16x4 hv = *(const s16x4*)(h + (size_t)w * 256 + lane * 4);
  float x0 = bf2f((unsigned short)hv.x), x1 = bf2f((unsigned short)hv.y);
  float x2 = bf2f((unsigned short)hv.z), x3 = bf2f((unsigned short)hv.w);
  int k = lane * 4;
  float l0 = x0 * W[(k + 0) * 2 + 0] + x1 * W[(k + 1) * 2 + 0] +
             x2 * W[(k + 2) * 2 + 0] + x3 * W[(k + 3) * 2 + 0];
  float l1 = x0 * W[(k + 0) * 2 + 1] + x1 * W[(k + 1) * 2 + 1] +
             x2 * W[(k + 2) * 2 + 1] + x3 * W[(k + 3) * 2 + 1];
  #pragma unroll
  for (int m = 1; m < 64; m <<= 1) {
    l0 += __shfl_xor(l0, m, 64);
    l1 += __shfl_xor(l1, m, 64);
  }
  if (lane == 0) {
    l0 += b[0]; l1 += b[1];
    float mx = fmaxf(l0, l1);
    float e0 = expf(l0 - mx), e1 = expf(l1 - mx);
    float s = e0 + e1;
    logits[(size_t)w * 2 + 0] = l0;
    logits[(size_t)w * 2 + 1] = l1;
    soft[(size_t)w * 2 + 0] = e0 / s;
    soft[(size_t)w * 2 + 1] = e1 / s;
  }
}

__global__ void decode3_kernel(const unsigned short* __restrict__ h, const float* __restrict__ W,
                               const float* __restrict__ b, float* __restrict__ logits,
                               float* __restrict__ soft, int n) {
  int w = (blockIdx.x * blockDim.x + threadIdx.x) >> 6;
  int lane = threadIdx.x & 63;
  if (w >= n) return;
  s16x4 hv = *(const s16x4*)(h + (size_t)w * 256 + lane * 4);
  float x0 = bf2f((unsigned short)hv.x), x1 = bf2f((unsigned short)hv.y);
  float x2 = bf2f((unsigned short)hv.z), x3 = bf2f((unsigned short)hv.w);
  int k = lane * 4;
  float l0 = x0 * W[(k + 0) * 3 + 0] + x1 * W[(k + 1) * 3 + 0] +
             x2 * W[(k + 2) * 3 + 0] + x3 * W[(k + 3) * 3 + 0];
  float l1 = x0 * W[(k + 0) * 3 + 1] + x1 * W[(k + 1) * 3 + 1] +
             x2 * W[(k + 2) * 3 + 1] + x3 * W[(k + 3) * 3 + 1];
  float l2 = x0 * W[(k + 0) * 3 + 2] + x1 * W[(k + 1) * 3 + 2] +
             x2 * W[(k + 2) * 3 + 2] + x3 * W[(k + 3) * 3 + 2];
  #pragma unroll
  for (int m = 1; m < 64; m <<= 1) {
    l0 += __shfl_xor(l0, m, 64);
    l1 += __shfl_xor(l1, m, 64);
    l2 += __shfl_xor(l2, m, 64);
  }
  if (lane == 0) {
    l0 += b[0]; l1 += b[1]; l2 += b[2];
    float mx = fmaxf(fmaxf(l0, l1), l2);
    float e0 = expf(l0 - mx), e1 = expf(l1 - mx), e2 = expf(l2 - mx);
    float s = e0 + e1 + e2;
    logits[(size_t)w * 3 + 0] = l0;
    logits[(size_t)w * 3 + 1] = l1;
    logits[(size_t)w * 3 + 2] = l2;
    soft[(size_t)w * 3 + 0] = e0 / s;
    soft[(size_t)w * 3 + 1] = e1 / s;
    soft[(size_t)w * 3 + 2] = e2 / s;
  }
}

// ---------------------------------------------------------------- host
extern "C" void kernel_launch(void* const* d_in, const int* in_sizes, int n_in,
                              void* d_out, int out_size, void* d_ws, size_t ws_size,
                              hipStream_t stream) {
  (void)in_sizes; (void)n_in; (void)out_size; (void)ws_size;
  const int*   c_labels  = (const int*)  d_in[0];
  const float* c_content = (const float*)d_in[1];
  const int*   a_labels  = (const int*)  d_in[2];
  const float* a_content = (const float*)d_in[3];
  const int*   edges[6];
  for (int r = 0; r < 6; ++r) edges[r] = (const int*)d_in[4 + r];
  const float* c_lbl_emb = (const float*)d_in[10];
  const float* c_enc_W   = (const float*)d_in[11];
  const float* c_enc_b   = (const float*)d_in[12];
  const float* a_lbl_emb = (const float*)d_in[13];
  const float* a_enc_W   = (const float*)d_in[14];
  const float* a_enc_b   = (const float*)d_in[15];
  const float* t_emb     = (const float*)d_in[16];
  const float* W_rel     = (const float*)d_in[17];
  const float* b_rel     = (const float*)d_in[18];
  const float* dec_W     = (const float*)d_in[19];
  const float* dec_b     = (const float*)d_in[20];
  const float* adec_W    = (const float*)d_in[21];
  const float* adec_b    = (const float*)d_in[22];
  float* out = (float*)d_out;

  static const int E_CNT[6]    = {200000, 400000, 200000, 200000, 50000, 50000};
  static const int REL_DSTN[6] = {N_CFG, N_AST, N_CFG, N_AST, N_TEST, N_CFG};

  char* ws = (char*)d_ws;
  size_t off = 0;
  auto alloc = [&](size_t bytes) -> void* {
    void* p = ws + off;
    off += (bytes + 255) & ~(size_t)255;
    return p;
  };
  unsigned short* buf0 = (unsigned short*)alloc((size_t)NNODE * 256 * 2);
  unsigned short* buf1 = (unsigned short*)alloc((size_t)NNODE * 256 * 2);
  unsigned short* Abuf = (unsigned short*)alloc((size_t)200064 * 512 * 2);
  unsigned short* Wt   = (unsigned short*)alloc((size_t)5 * 6 * 256 * 256 * 2);
  unsigned short* WtEc = (unsigned short*)alloc((size_t)128 * 320 * 2);
  unsigned short* WtEa = (unsigned short*)alloc((size_t)128 * 320 * 2);
  float*          bsum = (float*)alloc((size_t)5 * 3 * 256 * 4);
  int* rowptr[6];
  int* srcidx[6];
  for (int r = 0; r < 6; ++r) rowptr[r] = (int*)alloc((size_t)(REL_DSTN[r] + 1) * 4);
  for (int r = 0; r < 6; ++r) srcidx[r] = (int*)alloc((size_t)E_CNT[r] * 4);
  int* cursor = (int*)alloc((size_t)(N_AST + 1) * 4);

  // weights -> bf16; bias sums
  wt_kernel<<<CDIV(5 * 6 * 256 * 256, 256), 256, 0, stream>>>(W_rel, Wt);
  wtenc_kernel<<<CDIV(128 * 320, 256), 256, 0, stream>>>(c_enc_W, WtEc);
  wtenc_kernel<<<CDIV(128 * 320, 256), 256, 0, stream>>>(a_enc_W, WtEa);
  bsum_kernel<<<CDIV(5 * 3 * 256, 256), 256, 0, stream>>>(b_rel, bsum);

  // CSR (dst-sorted) per relation
  for (int r = 0; r < 6; ++r) {
    int nd = REL_DSTN[r], E = E_CNT[r];
    const int* esrc = edges[r];
    const int* edst = edges[r] + E;
    zero_int_kernel<<<CDIV(nd, 256), 256, 0, stream>>>(cursor, nd);
    hist_kernel<<<CDIV(E, 256), 256, 0, stream>>>(edst, E, cursor);
    scan_kernel<<<1, 1024, 0, stream>>>(cursor, rowptr[r], nd);
    copy_int_kernel<<<CDIV(nd, 256), 256, 0, stream>>>(cursor, rowptr[r], nd);
    scatter_kernel<<<CDIV(E, 256), 256, 0, stream>>>(esrc, edst, E, cursor, srcidx[r]);
  }

  const size_t OFF_CFG = 0;
  const size_t OFF_AST = (size_t)N_CFG * 256;
  const size_t OFF_TST = (size_t)(N_CFG + N_AST) * 256;

  // encoders -> buf0 (bf16)
  gather_lbl_kernel<<<CDIV(N_CFG * 32, 256), 256, 0, stream>>>(c_labels, c_lbl_emb, buf0 + OFF_CFG, N_CFG);
  gather_lbl_kernel<<<CDIV(N_AST * 32, 256), 256, 0, stream>>>(a_labels, a_lbl_emb, buf0 + OFF_AST, N_AST);
  enc_mfma_kernel<<<CDIV(N_CFG, 128), 256, 0, stream>>>(c_content, N_CFG, WtEc, c_enc_b, buf0 + OFF_CFG);
  enc_mfma_kernel<<<CDIV(N_AST, 128), 256, 0, stream>>>(a_content, N_AST, WtEa, a_enc_b, buf0 + OFF_AST);
  bcast_temb_kernel<<<CDIV(N_TEST * 64, 256), 256, 0, stream>>>(t_emb, buf0 + OFF_TST);

  unsigned short* h_in = buf0;
  unsigned short* h_out = buf1;
  for (int l = 0; l < 5; ++l) {
    bool use_res = (l == 1 || l == 3);
    const unsigned short* WtL = Wt + (size_t)l * 6 * 256 * 256;
    // dst cfg: rels 0(cc: src cfg), 2(ac: src ast), 5(tc: src test); K = 768
    agg_fused_kernel<<<CDIV(N_CFG, 4), 256, 0, stream>>>(
        h_in + OFF_CFG, rowptr[0], srcidx[0],
        h_in + OFF_AST, rowptr[2], srcidx[2],
        h_in + OFF_TST, rowptr[5], srcidx[5],
        3, Abuf, 768, N_CFG);
    gemm_mfma_kernel<<<CDIV(N_CFG, 128) * 2, 256, 0, stream>>>(
        Abuf, N_CFG, 768, WtL, bsum + (size_t)(l * 3 + 0) * 256, 0, 2, 5,
        use_res ? h_in + OFF_CFG : nullptr, h_out + OFF_CFG);
    // dst ast: rels 1(aa: src ast), 3(ca: src cfg); K = 512
    agg_fused_kernel<<<CDIV(N_AST, 4), 256, 0, stream>>>(
        h_in + OFF_AST, rowptr[1], srcidx[1],
        h_in + OFF_CFG, rowptr[3], srcidx[3],
        (const unsigned short*)nullptr, (const int*)nullptr, (const int*)nullptr,
        2, Abuf, 512, N_AST);
    gemm_mfma_kernel<<<CDIV(N_AST, 128) * 2, 256, 0, stream>>>(
        Abuf, N_AST, 512, WtL, bsum + (size_t)(l * 3 + 1) * 256, 1, 3, -1,
        use_res ? h_in + OFF_AST : nullptr, h_out + OFF_AST);
    // dst test: rel 4(ct: src cfg); K = 256
    agg_fused_kernel<<<CDIV(N_TEST, 4), 256, 0, stream>>>(
        h_in + OFF_CFG, rowptr[4], srcidx[4],
        (const unsigned short*)nullptr, (const int*)nullptr, (const int*)nullptr,
        (const unsigned short*)nullptr, (const int*)nullptr, (const int*)nullptr,
        1, Abuf, 256, N_TEST);
    gemm_mfma_kernel<<<CDIV(N_TEST, 128) * 2, 256, 0, stream>>>(
        Abuf, N_TEST, 256, WtL, bsum + (size_t)(l * 3 + 2) * 256, 4, -1, -1,
        use_res ? h_in + OFF_TST : nullptr, h_out + OFF_TST);
    unsigned short* t = h_in; h_in = h_out; h_out = t;
  }

  decode2_kernel<<<CDIV(N_CFG, 4), 256, 0, stream>>>(h_in + OFF_CFG, dec_W, dec_b,
                                                     out, out + 100000, N_CFG);
  decode3_kernel<<<CDIV(N_AST, 4), 256, 0, stream>>>(h_in + OFF_AST, adec_W, adec_b,
                                                     out + 200000, out + 800000, N_AST);
}